// Round 11
// baseline (1194.318 us; speedup 1.0000x reference)
//
#include <hip/hip_runtime.h>
#include <hip/hip_bf16.h>
#include <stdint.h>

#define NTOK 32768
#define HD 1024
#define FD 512
#define NEXP 8
#define TAU 0.05f
#define TAU2 4e-4f

typedef __attribute__((ext_vector_type(8))) short short8;
typedef __attribute__((ext_vector_type(4))) float f32x4;

__device__ __forceinline__ short f2bh(float f) {
  uint32_t u = __float_as_uint(f);
  return (short)((u + 0x7fffu + ((u >> 16) & 1u)) >> 16);
}
__device__ __forceinline__ float bh2f(short h) {
  return __uint_as_float(((uint32_t)(uint16_t)h) << 16);
}

__device__ __forceinline__ void gl16(void* lds, const void* g) {
  __builtin_amdgcn_global_load_lds(
      (const __attribute__((address_space(1))) void*)g,
      (__attribute__((address_space(3))) void*)lds, 16, 0, 0);
}

// ---------------------------------------------------------------------------
__global__ __launch_bounds__(256) void k_convert(const float* __restrict__ x,
                                                 short* __restrict__ xbf) {
  size_t i = ((size_t)blockIdx.x * 256 + threadIdx.x) * 8;
  f32x4 v0 = *(const f32x4*)(x + i);
  f32x4 v1 = *(const f32x4*)(x + i + 4);
  short8 o;
#pragma unroll
  for (int q = 0; q < 4; ++q) { o[q] = f2bh(v0[q]); o[4 + q] = f2bh(v1[q]); }
  *(short8*)(xbf + i) = o;
}

// ---------------------------------------------------------------------------
__global__ __launch_bounds__(256) void k_transpose(
    const float* __restrict__ src, short* __restrict__ dst, int rows, int cols) {
  __shared__ float tile[32][33];
  size_t msz = (size_t)rows * cols;
  src += (size_t)blockIdx.z * msz;
  dst += (size_t)blockIdx.z * msz;
  int c0 = blockIdx.x * 32, r0 = blockIdx.y * 32;
  int tx = threadIdx.x & 31, ty = threadIdx.x >> 5;
#pragma unroll
  for (int i = 0; i < 32; i += 8)
    tile[ty + i][tx] = src[(size_t)(r0 + ty + i) * cols + c0 + tx];
  __syncthreads();
#pragma unroll
  for (int i = 0; i < 32; i += 8)
    dst[(size_t)(c0 + ty + i) * rows + r0 + tx] = f2bh(tile[tx][ty + i]);
}

// ---------------------------------------------------------------------------
__global__ __launch_bounds__(256) void k_transpose_split(
    const float* __restrict__ src, short* __restrict__ dstH,
    short* __restrict__ dstL, int rows, int cols) {
  __shared__ float tile[32][33];
  int c0 = blockIdx.x * 32, r0 = blockIdx.y * 32;
  int tx = threadIdx.x & 31, ty = threadIdx.x >> 5;
#pragma unroll
  for (int i = 0; i < 32; i += 8)
    tile[ty + i][tx] = src[(size_t)(r0 + ty + i) * cols + c0 + tx];
  __syncthreads();
#pragma unroll
  for (int i = 0; i < 32; i += 8) {
    float v = tile[tx][ty + i];
    short h = f2bh(v);
    size_t di = (size_t)(c0 + ty + i) * rows + r0 + tx;
    dstH[di] = h;
    dstL[di] = f2bh(v - bh2f(h));
  }
}

// ---------------------------------------------------------------------------
// GEMM1: unchanged R10 version (128x128, single-buffer, swizzle, setprio,
// MFMA logits epilogue).
// ---------------------------------------------------------------------------
template <bool ABF>
__global__ __launch_bounds__(256) void k_gemm1(
    const short* __restrict__ xbf, const float* __restrict__ xf,
    const short* __restrict__ W1T, const float* __restrict__ b1,
    const float* __restrict__ W2, float* __restrict__ part) {
  __shared__ __align__(16) char smem[39168];

  const int tid = threadIdx.x;
  const int lane = tid & 63, wave = tid >> 6;
  const int wr = wave >> 1, wc = wave & 1;
  const int fr = lane & 15, fg = lane >> 4;
  const int bx = ((blockIdx.x & 7) << 5) | (blockIdx.x >> 3);  // T1, 256=8*32
  const int m0 = bx * 128, n0 = blockIdx.y * 128;
  const int by = blockIdx.y;

  const int r0 = wave * 16 + (lane >> 2);
  const int lsw = (((lane & 3) ^ ((lane >> 3) & 3)) << 3);
  const short* b0p = W1T + (size_t)(n0 + r0) * HD + lsw;
  const short* b1p = W1T + (size_t)(n0 + r0 + 64) * HD + lsw;

  const short* a0p = nullptr; const short* a1p = nullptr;
  const float* aF = nullptr;
  int ar = 0, ah = 0, p0e = 0, p1e = 0;
  if constexpr (ABF) {
    a0p = xbf + (size_t)(m0 + r0) * HD + lsw;
    a1p = xbf + (size_t)(m0 + r0 + 64) * HD + lsw;
  } else {
    ar = tid >> 1; ah = tid & 1;
    aF = xf + (size_t)(m0 + ar) * HD + ah * 16;
    int s = (ar >> 1) & 3;
    p0e = ((2 * ah) ^ s) << 3;
    p1e = p0e ^ 8;
  }

  f32x4 acc[4][4];
#pragma unroll
  for (int i = 0; i < 4; ++i)
#pragma unroll
    for (int j = 0; j < 4; ++j) acc[i][j] = (f32x4){0.f, 0.f, 0.f, 0.f};

  const int csw = (fr >> 1) & 3;
  for (int k0 = 0; k0 < HD; k0 += 32) {
    gl16(smem + 8192 + wave * 1024, b0p + k0);
    gl16(smem + 12288 + wave * 1024, b1p + k0);
    if constexpr (ABF) {
      gl16(smem + wave * 1024, a0p + k0);
      gl16(smem + 4096 + wave * 1024, a1p + k0);
    } else {
      f32x4 u0 = *(const f32x4*)(aF + k0);
      f32x4 u1 = *(const f32x4*)(aF + k0 + 4);
      f32x4 u2 = *(const f32x4*)(aF + k0 + 8);
      f32x4 u3 = *(const f32x4*)(aF + k0 + 12);
      short8 s0, s1;
#pragma unroll
      for (int q = 0; q < 4; ++q) {
        s0[q] = f2bh(u0[q]); s0[4 + q] = f2bh(u1[q]);
        s1[q] = f2bh(u2[q]); s1[4 + q] = f2bh(u3[q]);
      }
      short* As = (short*)smem;
      *(short8*)(As + ar * 32 + p0e) = s0;
      *(short8*)(As + ar * 32 + p1e) = s1;
    }
    __syncthreads();
    {
      const short* As = (const short*)smem;
      const short* Bs = (const short*)(smem + 8192);
      short8 af[4], bf4[4];
#pragma unroll
      for (int i = 0; i < 4; ++i) {
        af[i]  = *(const short8*)(As + (wr * 64 + i * 16 + fr) * 32 + ((fg ^ csw) << 3));
        bf4[i] = *(const short8*)(Bs + (wc * 64 + i * 16 + fr) * 32 + ((fg ^ csw) << 3));
      }
      __builtin_amdgcn_s_setprio(1);
#pragma unroll
      for (int i = 0; i < 4; ++i)
#pragma unroll
        for (int j = 0; j < 4; ++j)
          acc[i][j] = __builtin_amdgcn_mfma_f32_16x16x32_bf16(af[i], bf4[j], acc[i][j], 0, 0, 0);
      __builtin_amdgcn_s_setprio(0);
    }
    __syncthreads();
  }

  short* hbf = (short*)smem;            // [128][136] bf16
  short* W2b = (short*)(smem + 34816);  // [16][136]
  float b1j[4];
#pragma unroll
  for (int j = 0; j < 4; ++j) b1j[j] = b1[n0 + wc * 64 + j * 16 + fr];
  for (int q = tid; q < 2048; q += 256) {
    int col = q >> 7, k = q & 127;
    W2b[col * 136 + k] = (col < 8) ? f2bh(W2[(size_t)(n0 + k) * 8 + col]) : (short)0;
  }
#pragma unroll
  for (int i = 0; i < 4; ++i)
#pragma unroll
    for (int j = 0; j < 4; ++j) {
      int col = wc * 64 + j * 16 + fr;
#pragma unroll
      for (int q = 0; q < 4; ++q)
        hbf[(wr * 64 + i * 16 + fg * 4 + q) * 136 + col] =
            f2bh(fmaxf(acc[i][j][q] + b1j[j], 0.f));
    }
  __syncthreads();
#pragma unroll
  for (int rg = 0; rg < 2; ++rg) {
    int row16 = wave * 32 + rg * 16;
    f32x4 accl = (f32x4){0.f, 0.f, 0.f, 0.f};
#pragma unroll
    for (int kk = 0; kk < 4; ++kk) {
      short8 a = *(const short8*)(hbf + (row16 + fr) * 136 + kk * 32 + fg * 8);
      short8 b = *(const short8*)(W2b + fr * 136 + kk * 32 + fg * 8);
      accl = __builtin_amdgcn_mfma_f32_16x16x32_bf16(a, b, accl, 0, 0, 0);
    }
    if (fr < 8) {
      float* pp = part + (size_t)(m0 + row16 + fg * 4) * 32 + by * 8 + fr;
#pragma unroll
      for (int q = 0; q < 4; ++q) pp[(size_t)q * 32] = accl[q];
    }
  }
}

// ---------------------------------------------------------------------------
__global__ __launch_bounds__(256) void k_combine(
    const float* __restrict__ part, const float* __restrict__ b2,
    int* __restrict__ sel, int* __restrict__ flagged, int* __restrict__ nflag) {
  int t = blockIdx.x * 256 + threadIdx.x;
  const float* p = part + (size_t)t * 32;
  float lg[8];
#pragma unroll
  for (int e = 0; e < 8; ++e) lg[e] = p[e] + p[8 + e] + p[16 + e] + p[24 + e] + b2[e];
  int be = 0; float best = lg[0];
#pragma unroll
  for (int e = 1; e < 8; ++e) if (lg[e] > best) { best = lg[e]; be = e; }
  float second = -3.4e38f;
#pragma unroll
  for (int e = 0; e < 8; ++e) if (e != be && lg[e] > second) second = lg[e];
  sel[t] = be;
  if (best - second < TAU) {
    int ix = atomicAdd(nflag, 1);
    if (ix < NTOK) flagged[ix] = t;
  }
}

// ---------------------------------------------------------------------------
// Tier-A: bf16x3 re-GEMM of flagged tokens (unchanged).
// ---------------------------------------------------------------------------
__global__ __launch_bounds__(256) void k_gemmR(
    const float* __restrict__ x, const short* __restrict__ W1hT,
    const short* __restrict__ W1lT, const float* __restrict__ b1,
    const float* __restrict__ W2, const int* __restrict__ flagged,
    const int* __restrict__ nflag, float* __restrict__ partR) {
  __shared__ __align__(16) char smem[37888];
  __shared__ int toks[128];
  short* Ah = (short*)smem;
  short* Al = (short*)(smem + 8192);

  int nf = *nflag; if (nf > NTOK) nf = NTOK;
  const int m0 = blockIdx.x * 128;
  if (m0 >= nf) return;
  const int tid = threadIdx.x;
  if (tid < 128) {
    int s = m0 + tid;
    toks[tid] = flagged[s < nf ? s : nf - 1];
  }
  __syncthreads();

  const int lane = tid & 63, wave = tid >> 6;
  const int wr = wave >> 1, wc = wave & 1;
  const int fr = lane & 15, fg = lane >> 4;
  const int n0 = blockIdx.y * 128;
  const int by = blockIdx.y;

  const int off0 = wave * 1024 + lane * 16;
  const int off1 = off0 + 4096;
  const int r0 = off0 >> 6, c0 = (off0 & 63) >> 1;
  const int r1 = off1 >> 6, c1 = (off1 & 63) >> 1;
  const short* bh0p = W1hT + (size_t)(n0 + r0) * HD + c0;
  const short* bh1p = W1hT + (size_t)(n0 + r1) * HD + c1;
  const short* bl0p = W1lT + (size_t)(n0 + r0) * HD + c0;
  const short* bl1p = W1lT + (size_t)(n0 + r1) * HD + c1;
  char* ldsBh0 = smem + 16384 + wave * 1024;
  char* ldsBh1 = smem + 16384 + wave * 1024 + 4096;
  char* ldsBl0 = smem + 24576 + wave * 1024;
  char* ldsBl1 = smem + 24576 + wave * 1024 + 4096;
  const int ar = tid >> 1, ah2 = tid & 1;
  const float* aF = x + (size_t)toks[ar] * HD + ah2 * 16;

  f32x4 acc[4][4];
#pragma unroll
  for (int i = 0; i < 4; ++i)
#pragma unroll
    for (int j = 0; j < 4; ++j) acc[i][j] = (f32x4){0.f, 0.f, 0.f, 0.f};

  for (int k0 = 0; k0 < HD; k0 += 32) {
    gl16(ldsBh0, bh0p + k0);
    gl16(ldsBh1, bh1p + k0);
    gl16(ldsBl0, bl0p + k0);
    gl16(ldsBl1, bl1p + k0);
    f32x4 u0 = *(const f32x4*)(aF + k0);
    f32x4 u1 = *(const f32x4*)(aF + k0 + 4);
    f32x4 u2 = *(const f32x4*)(aF + k0 + 8);
    f32x4 u3 = *(const f32x4*)(aF + k0 + 12);
    short8 sh0, sh1, sl0, sl1;
#pragma unroll
    for (int q = 0; q < 4; ++q) {
      { float f = u0[q]; short h = f2bh(f); sh0[q]     = h; sl0[q]     = f2bh(f - bh2f(h)); }
      { float f = u1[q]; short h = f2bh(f); sh0[4 + q] = h; sl0[4 + q] = f2bh(f - bh2f(h)); }
      { float f = u2[q]; short h = f2bh(f); sh1[q]     = h; sl1[q]     = f2bh(f - bh2f(h)); }
      { float f = u3[q]; short h = f2bh(f); sh1[4 + q] = h; sl1[4 + q] = f2bh(f - bh2f(h)); }
    }
    *(short8*)(Ah + ar * 32 + ah2 * 16)     = sh0;
    *(short8*)(Ah + ar * 32 + ah2 * 16 + 8) = sh1;
    *(short8*)(Al + ar * 32 + ah2 * 16)     = sl0;
    *(short8*)(Al + ar * 32 + ah2 * 16 + 8) = sl1;
    __syncthreads();
    short8 af[4], alf[4], bf[4], blf[4];
#pragma unroll
    for (int i = 0; i < 4; ++i) {
      int row = (wr * 64 + i * 16 + fr) * 32 + fg * 8;
      af[i]  = *(const short8*)(Ah + row);
      alf[i] = *(const short8*)(Al + row);
      int rowb = (wc * 64 + i * 16 + fr) * 32 + fg * 8;
      bf[i]  = *(const short8*)((short*)(smem + 16384) + rowb);
      blf[i] = *(const short8*)((short*)(smem + 24576) + rowb);
    }
#pragma unroll
    for (int i = 0; i < 4; ++i)
#pragma unroll
      for (int j = 0; j < 4; ++j) {
        acc[i][j] = __builtin_amdgcn_mfma_f32_16x16x32_bf16(af[i],  bf[j],  acc[i][j], 0, 0, 0);
        acc[i][j] = __builtin_amdgcn_mfma_f32_16x16x32_bf16(af[i],  blf[j], acc[i][j], 0, 0, 0);
        acc[i][j] = __builtin_amdgcn_mfma_f32_16x16x32_bf16(alf[i], bf[j],  acc[i][j], 0, 0, 0);
      }
    __syncthreads();
  }

  float* hl64 = (float*)smem;            // [64][129]
  float* W2c  = (float*)(smem + 33024);  // [128][8]
  *(f32x4*)(W2c + tid * 4) = *(const f32x4*)(W2 + (size_t)n0 * NEXP + tid * 4);
  float b1j[4];
#pragma unroll
  for (int j = 0; j < 4; ++j) b1j[j] = b1[n0 + wc * 64 + j * 16 + fr];

  for (int p = 0; p < 2; ++p) {
    if (wr == p) {
#pragma unroll
      for (int i = 0; i < 4; ++i)
#pragma unroll
        for (int j = 0; j < 4; ++j) {
          int col = wc * 64 + j * 16 + fr;
#pragma unroll
          for (int q = 0; q < 4; ++q)
            hl64[(i * 16 + fg * 4 + q) * 129 + col] = fmaxf(acc[i][j][q] + b1j[j], 0.f);
        }
    }
    __syncthreads();
    if (tid < 128) {
      int r2 = tid & 63, eh = tid >> 6;
      const float* hrow = hl64 + r2 * 129;
      const float* wcp = W2c + eh * 4;
      float s0 = 0.f, s1 = 0.f, s2 = 0.f, s3 = 0.f;
      for (int f = 0; f < 128; ++f) {
        float hv = hrow[f];
        s0 += hv * wcp[f * 8 + 0];
        s1 += hv * wcp[f * 8 + 1];
        s2 += hv * wcp[f * 8 + 2];
        s3 += hv * wcp[f * 8 + 3];
      }
      float* pp = partR + (size_t)(m0 + p * 64 + r2) * 32 + by * 8 + eh * 4;
      pp[0] = s0; pp[1] = s1; pp[2] = s2; pp[3] = s3;
    }
    __syncthreads();
  }
}

// ---------------------------------------------------------------------------
__global__ __launch_bounds__(256) void k_combineR(
    const float* __restrict__ partR, const float* __restrict__ b2,
    const int* __restrict__ flagged, const int* __restrict__ nflag,
    int* __restrict__ sel, int* __restrict__ flagged2, int* __restrict__ nflag2) {
  int nf = *nflag; if (nf > NTOK) nf = NTOK;
  int s = blockIdx.x * 256 + threadIdx.x;
  if (s >= nf) return;
  int t = flagged[s];
  const float* p = partR + (size_t)s * 32;
  float lg[8];
#pragma unroll
  for (int e = 0; e < 8; ++e) lg[e] = p[e] + p[8 + e] + p[16 + e] + p[24 + e] + b2[e];
  int be = 0; float best = lg[0];
#pragma unroll
  for (int e = 1; e < 8; ++e) if (lg[e] > best) { best = lg[e]; be = e; }
  float second = -3.4e38f;
#pragma unroll
  for (int e = 0; e < 8; ++e) if (e != be && lg[e] > second) second = lg[e];
  sel[t] = be;
  if (best - second < TAU2) {
    int ix = atomicAdd(nflag2, 1);
    if (ix < NTOK) flagged2[ix] = t;
  }
}

// ---------------------------------------------------------------------------
__global__ __launch_bounds__(256) void k_recomputeB(
    const float* __restrict__ x, const float* __restrict__ W1,
    const float* __restrict__ b1, const float* __restrict__ W2,
    const float* __restrict__ b2, const int* __restrict__ flagged2,
    const int* __restrict__ nflag2, int* __restrict__ sel) {
  __shared__ float xs[1024];
  __shared__ double hs[512];
  __shared__ double red[8][32];
  __shared__ double lgd[8];
  int nf = *nflag2; if (nf > NTOK) nf = NTOK;
  const int tid = threadIdx.x;
  for (int ti = blockIdx.x; ti < nf; ti += gridDim.x) {
    int t = flagged2[ti];
    __syncthreads();
    for (int q = tid; q < 1024; q += 256) xs[q] = x[(size_t)t * HD + q];
    __syncthreads();
    int f0 = tid * 2;
    double a0 = 0.0, a1 = 0.0;
    for (int h = 0; h < 1024; h += 4) {
      float2 w0 = *(const float2*)(W1 + (size_t)(h + 0) * FD + f0);
      float2 w1 = *(const float2*)(W1 + (size_t)(h + 1) * FD + f0);
      float2 w2 = *(const float2*)(W1 + (size_t)(h + 2) * FD + f0);
      float2 w3 = *(const float2*)(W1 + (size_t)(h + 3) * FD + f0);
      double x0 = (double)xs[h], x1 = (double)xs[h + 1];
      double x2 = (double)xs[h + 2], x3 = (double)xs[h + 3];
      a0 += x0 * (double)w0.x; a1 += x0 * (double)w0.y;
      a0 += x1 * (double)w1.x; a1 += x1 * (double)w1.y;
      a0 += x2 * (double)w2.x; a1 += x2 * (double)w2.y;
      a0 += x3 * (double)w3.x; a1 += x3 * (double)w3.y;
    }
    a0 += (double)b1[f0]; a1 += (double)b1[f0 + 1];
    hs[f0]     = a0 > 0.0 ? a0 : 0.0;
    hs[f0 + 1] = a1 > 0.0 ? a1 : 0.0;
    __syncthreads();
    {
      int e = tid >> 5, c = tid & 31;
      int fb = c * 16;
      double s = 0.0;
#pragma unroll
      for (int ff = 0; ff < 16; ++ff)
        s += hs[fb + ff] * (double)W2[(size_t)(fb + ff) * 8 + e];
      red[e][c] = s;
    }
    __syncthreads();
    if (tid < 8) {
      double s = 0.0;
#pragma unroll
      for (int c = 0; c < 32; ++c) s += red[tid][c];
      lgd[tid] = s + (double)b2[tid];
    }
    __syncthreads();
    if (tid == 0) {
      int be = 0; double best = lgd[0];
#pragma unroll
      for (int e = 1; e < 8; ++e) if (lgd[e] > best) { best = lgd[e]; be = e; }
      sel[t] = be;
    }
    __syncthreads();
  }
}

// ---------------------------------------------------------------------------
__global__ __launch_bounds__(256) void k_compact(
    const int* __restrict__ sel, int* __restrict__ cnt, int* __restrict__ list) {
  __shared__ int wcnt[4][8];
  __shared__ int woff[4][8];
  __shared__ int bbase[8];
  const int tid = threadIdx.x, lane = tid & 63, wave = tid >> 6;
  const int t = blockIdx.x * 256 + tid;
  const int e = sel[t];
  const unsigned long long ltmask = (1ull << lane) - 1ull;
  int rank = 0;
#pragma unroll
  for (int e2 = 0; e2 < 8; ++e2) {
    unsigned long long m = __ballot(e == e2);
    if (e2 == e) rank = __popcll(m & ltmask);
    if (lane == 0) wcnt[wave][e2] = __popcll(m);
  }
  __syncthreads();
  if (tid < 8) {
    int s0 = wcnt[0][tid], s1 = wcnt[1][tid], s2 = wcnt[2][tid], s3 = wcnt[3][tid];
    woff[0][tid] = 0; woff[1][tid] = s0; woff[2][tid] = s0 + s1; woff[3][tid] = s0 + s1 + s2;
    bbase[tid] = atomicAdd(&cnt[tid], s0 + s1 + s2 + s3);
  }
  __syncthreads();
  list[(size_t)e * NTOK + bbase[e] + woff[wave][e] + rank] = t;
}

__global__ void k_build_desc(const int* __restrict__ cnt, int* __restrict__ desc,
                             int* __restrict__ ntl) {
  if (threadIdx.x == 0 && blockIdx.x == 0) {
    int n = 0;
    for (int e = 0; e < 8; ++e) {
      int m = (cnt[e] + 255) >> 8;   // 256-row tiles for gemm2 v2
      for (int i = 0; i < m; ++i) desc[n++] = (e << 16) | i;
    }
    *ntl = n;
  }
}

// ---------------------------------------------------------------------------
// GEMM2 v2: 256x256 tile, BK=32, 8 waves (512 thr), minimum-2-phase
// (double-buffered LDS, STAGE-next issued BEFORE compute, ONE
// __syncthreads per K-step whose implicit vmcnt(0) drains the prefetch
// after ~32 MFMA of cover). T2 swizzle reused from R10. Coalesced epilogue.
// ---------------------------------------------------------------------------
template <bool ABF>
__global__ __launch_bounds__(512, 2) void k_gemm2(
    const short* __restrict__ xbf, const float* __restrict__ xf,
    const short* __restrict__ WexpT, const float* __restrict__ expert_b,
    const int* __restrict__ cnt, const int* __restrict__ list,
    const int* __restrict__ desc, const int* __restrict__ ntl,
    float* __restrict__ out) {
  __shared__ __align__(16) char smem[65536];
  // Abuf[2]: [0,16K),[16K,32K). Bbuf[2]: [32K,48K),[48K,64K).
  const int bx = (blockIdx.x % 8) * 17 + blockIdx.x / 8;  // T1 bijective, 136=8*17
  if (bx >= *ntl) return;
  int dsc = desc[bx];
  int e = dsc >> 16, mt = dsc & 0xffff;
  int ce = cnt[e];
  int mb = mt * 256;
  int rows = ce - mb; if (rows > 256) rows = 256;

  const int tid = threadIdx.x;
  const int lane = tid & 63, wave = tid >> 6;
  const int wr = wave >> 2, wcol = wave & 3;      // 2M x 4N wave grid
  const int fr = lane & 15, fg = lane >> 4;
  const int n0 = blockIdx.y * 256;
  const size_t ebase = (size_t)e << 20;
  const int lr = lane >> 2;                                 // 0..15
  const int gc8 = (((lane & 3) ^ ((lane >> 3) & 3)) << 3);  // swizzled src chunk (elems)

  // B stage pointers: rows n0 + wave*32 + {0,16} + lr
  const short* bP0 = WexpT + ebase + (size_t)(n0 + wave * 32 + lr) * HD + gc8;
  const short* bP1 = bP0 + (size_t)16 * HD;

  // A stage pointers (gathered token rows)
  const short* aP0 = nullptr; const short* aP1 = nullptr;
  const float* aF = nullptr;
  int arow = 0, pc0 = 0, pc1 = 0;
  if constexpr (ABF) {
    int r0 = wave * 32 + lr, r1 = r0 + 16;
    int i0 = mb + r0; i0 = i0 < ce ? i0 : ce - 1;
    int i1 = mb + r1; i1 = i1 < ce ? i1 : ce - 1;
    aP0 = xbf + (size_t)list[(size_t)e * NTOK + i0] * HD + gc8;
    aP1 = xbf + (size_t)list[(size_t)e * NTOK + i1] * HD + gc8;
  } else {
    arow = tid >> 1;
    int idx = mb + arow; idx = idx < ce ? idx : ce - 1;
    aF = xf + (size_t)list[(size_t)e * NTOK + idx] * HD + (tid & 1) * 16;
    int c0 = (tid & 1) * 2, s = (arow >> 1) & 3;
    pc0 = (c0 ^ s) << 3; pc1 = ((c0 + 1) ^ s) << 3;
  }

  f32x4 acc[8][4];
#pragma unroll
  for (int i = 0; i < 8; ++i)
#pragma unroll
    for (int j = 0; j < 4; ++j) acc[i][j] = (f32x4){0.f, 0.f, 0.f, 0.f};

  auto STAGE = [&](int kt, int b) {
    const int k0 = kt * 32;
    gl16(smem + 32768 + b * 16384 + wave * 2048,        bP0 + k0);
    gl16(smem + 32768 + b * 16384 + wave * 2048 + 1024, bP1 + k0);
    if constexpr (ABF) {
      gl16(smem + b * 16384 + wave * 2048,        aP0 + k0);
      gl16(smem + b * 16384 + wave * 2048 + 1024, aP1 + k0);
    } else {
      f32x4 u0 = *(const f32x4*)(aF + k0);
      f32x4 u1 = *(const f32x4*)(aF + k0 + 4);
      f32x4 u2 = *(const f32x4*)(aF + k0 + 8);
      f32x4 u3 = *(const f32x4*)(aF + k0 + 12);
      short8 s0, s1;
#pragma unroll
      for (int q = 0; q < 4; ++q) {
        s0[q] = f2bh(u0[q]); s0[4 + q] = f2bh(u1[q]);
        s1[q] = f2bh(u2[q]); s1[4 + q] = f2bh(u3[q]);
      }
      short* As = (short*)(smem + b * 16384);
      *(short8*)(As + arow * 32 + pc0) = s0;
      *(short8*)(As + arow * 32 + pc1) = s1;
    }
  };
  const int csw = (fr >> 1) & 3;
  auto COMPUTE = [&](int b) {
    const short* As = (const short*)(smem + b * 16384);
    const short* Bs = (const short*)(smem + 32768 + b * 16384);
    short8 a[8], bb[4];
#pragma unroll
    for (int i = 0; i < 8; ++i)
      a[i] = *(const short8*)(As + (wr * 128 + i * 16 + fr) * 32 + ((fg ^ csw) << 3));
#pragma unroll
    for (int j = 0; j < 4; ++j)
      bb[j] = *(const short8*)(Bs + (wcol * 64 + j * 16 + fr) * 32 + ((fg ^ csw) << 3));
#pragma unroll
    for (int i = 0; i < 8; ++i)
#pragma unroll
      for (int j = 0; j < 4; ++j)
        acc[i][j] = __builtin_amdgcn_mfma_f32_16x16x32_bf16(a[i], bb[j], acc[i][j], 0, 0, 0);
  };

  // minimum-2-phase: prologue stage; per step {STAGE next; COMPUTE cur; barrier}
  STAGE(0, 0);
  __syncthreads();
  int cur = 0;
#pragma unroll 1
  for (int kt = 0; kt < 32; ++kt) {
    if (kt + 1 < 32) STAGE(kt + 1, cur ^ 1);
    COMPUTE(cur);
    __syncthreads();   // implicit vmcnt(0)+lgkmcnt(0): next tile ready, cur free
    cur ^= 1;
  }

  // Coalesced epilogue: 16 passes of 16 rows via [16][264] f32 LDS buffer.
  float ebv[4];
#pragma unroll
  for (int j = 0; j < 4; ++j)
    ebv[j] = expert_b[e * HD + n0 + wcol * 64 + j * 16 + fr];
  float* buf = (float*)smem;  // 16*264*4 = 16896 B
  const int row16 = tid >> 5, cc = tid & 31;
  const int listbase = (int)((size_t)e * NTOK) + mb;
#pragma unroll 1
  for (int p = 0; p < 16; ++p) {
    if (wr == (p >> 3)) {
      const int i = p & 7;
#pragma unroll
      for (int j = 0; j < 4; ++j) {
        int col = wcol * 64 + j * 16 + fr;
#pragma unroll
        for (int q = 0; q < 4; ++q)
          buf[(fg * 4 + q) * 264 + col] = acc[i][j][q] + ebv[j];
      }
    }
    __syncthreads();
    const int rr = p * 16 + row16;
    if (rr < rows) {
      int tok = list[listbase + rr];
      float* op = out + (size_t)tok * HD + n0 + cc * 8;
      *(f32x4*)op       = *(const f32x4*)(buf + row16 * 264 + cc * 8);
      *(f32x4*)(op + 4) = *(const f32x4*)(buf + row16 * 264 + cc * 8 + 4);
    }
    __syncthreads();
  }
}

// ---------------------------------------------------------------------------
extern "C" void kernel_launch(void* const* d_in, const int* in_sizes, int n_in,
                              void* d_out, int out_size, void* d_ws, size_t ws_size,
                              hipStream_t stream) {
  const float* x  = (const float*)d_in[0];
  const float* W1 = (const float*)d_in[1];
  const float* b1 = (const float*)d_in[2];
  const float* W2 = (const float*)d_in[3];
  const float* b2 = (const float*)d_in[4];
  const float* eW = (const float*)d_in[5];
  const float* eb = (const float*)d_in[6];
  float* out = (float*)d_out;
  char* ws = (char*)d_ws;

  const size_t XBF_BYTES = (size_t)NTOK * HD * 2;  // 67,108,864
  size_t need_rest = 16777216ull + 1048576 + 4194304 + 131072 * 3 + 1048576 + 4096;
  bool big = ws_size >= XBF_BYTES + need_rest;

  size_t off = 0;
  short* xbf = nullptr;
  if (big) { xbf = (short*)ws; off += XBF_BYTES; }
  short* WexpT  = (short*)(ws + off); off += 16777216;
  short* W1T    = (short*)(ws + off); off += 1048576;
  float* part   = (float*)(ws + off); off += 4194304;   // also partR (tier-A)
  int* sel      = (int*)(ws + off); off += 131072;
  int* flagged  = (int*)(ws + off); off += 131072;
  int* flagged2 = (int*)(ws + off); off += 131072;
  int* list     = (int*)(ws + off); off += 1048576;     // also W1lT before compact
  int* cnt      = (int*)(ws + off); off += 32;
  int* nflag    = (int*)(ws + off); off += 4;
  int* ntl      = (int*)(ws + off); off += 4;
  int* nflag2   = (int*)(ws + off); off += 24;
  int* desc     = (int*)(ws + off); off += 1088;
  if (ws_size < off) return;

  short* W1lT = (short*)list;  // 1 MB, live until k_compact

  hipMemsetAsync(cnt, 0, 44, stream);  // cnt[8], nflag, ntl, nflag2

  dim3 b256(256), b512(512);
  if (big) k_convert<<<dim3(16384), b256, 0, stream>>>(x, xbf);
  k_transpose_split<<<dim3(16, 32), b256, 0, stream>>>(W1, W1T, W1lT, 1024, 512);
  k_transpose<<<dim3(32, 32, 8), b256, 0, stream>>>(eW, WexpT, 1024, 1024);
  if (big)
    k_gemm1<true><<<dim3(256, 4), b256, 0, stream>>>(xbf, nullptr, W1T, b1, W2, part);
  else
    k_gemm1<false><<<dim3(256, 4), b256, 0, stream>>>(nullptr, x, W1T, b1, W2, part);
  k_combine<<<dim3(128), b256, 0, stream>>>(part, b2, sel, flagged, nflag);
  k_gemmR<<<dim3(256, 4), b256, 0, stream>>>(x, W1T, W1lT, b1, W2, flagged, nflag, part);
  k_combineR<<<dim3(128), b256, 0, stream>>>(part, b2, flagged, nflag, sel, flagged2, nflag2);
  k_recomputeB<<<dim3(128), b256, 0, stream>>>(x, W1, b1, W2, b2, flagged2, nflag2, sel);
  k_compact<<<dim3(128), b256, 0, stream>>>(sel, cnt, list);
  k_build_desc<<<dim3(1), dim3(64), 0, stream>>>(cnt, desc, ntl);
  if (big)
    k_gemm2<true><<<dim3(136, 4), b512, 0, stream>>>(xbf, nullptr, WexpT, eb, cnt, list, desc, ntl, out);
  else
    k_gemm2<false><<<dim3(136, 4), b512, 0, stream>>>(nullptr, x, WexpT, eb, cnt, list, desc, ntl, out);
}

// Round 12
// 1193.676 us; speedup vs baseline: 1.0005x; 1.0005x over previous
//
#include <hip/hip_runtime.h>
#include <hip/hip_bf16.h>
#include <stdint.h>

#define NTOK 32768
#define HD 1024
#define FD 512
#define NEXP 8
#define TAU 0.05f
#define TAU2 4e-4f

typedef __attribute__((ext_vector_type(8))) short short8;
typedef __attribute__((ext_vector_type(4))) float f32x4;

__device__ __forceinline__ short f2bh(float f) {
  uint32_t u = __float_as_uint(f);
  return (short)((u + 0x7fffu + ((u >> 16) & 1u)) >> 16);
}
__device__ __forceinline__ float bh2f(short h) {
  return __uint_as_float(((uint32_t)(uint16_t)h) << 16);
}

__device__ __forceinline__ void gl16(void* lds, const void* g) {
  __builtin_amdgcn_global_load_lds(
      (const __attribute__((address_space(1))) void*)g,
      (__attribute__((address_space(3))) void*)lds, 16, 0, 0);
}

// ---------------------------------------------------------------------------
__global__ __launch_bounds__(256) void k_convert(const float* __restrict__ x,
                                                 short* __restrict__ xbf) {
  size_t i = ((size_t)blockIdx.x * 256 + threadIdx.x) * 8;
  f32x4 v0 = *(const f32x4*)(x + i);
  f32x4 v1 = *(const f32x4*)(x + i + 4);
  short8 o;
#pragma unroll
  for (int q = 0; q < 4; ++q) { o[q] = f2bh(v0[q]); o[4 + q] = f2bh(v1[q]); }
  *(short8*)(xbf + i) = o;
}

// ---------------------------------------------------------------------------
__global__ __launch_bounds__(256) void k_transpose(
    const float* __restrict__ src, short* __restrict__ dst, int rows, int cols) {
  __shared__ float tile[32][33];
  size_t msz = (size_t)rows * cols;
  src += (size_t)blockIdx.z * msz;
  dst += (size_t)blockIdx.z * msz;
  int c0 = blockIdx.x * 32, r0 = blockIdx.y * 32;
  int tx = threadIdx.x & 31, ty = threadIdx.x >> 5;
#pragma unroll
  for (int i = 0; i < 32; i += 8)
    tile[ty + i][tx] = src[(size_t)(r0 + ty + i) * cols + c0 + tx];
  __syncthreads();
#pragma unroll
  for (int i = 0; i < 32; i += 8)
    dst[(size_t)(c0 + ty + i) * rows + r0 + tx] = f2bh(tile[tx][ty + i]);
}

// ---------------------------------------------------------------------------
__global__ __launch_bounds__(256) void k_transpose_split(
    const float* __restrict__ src, short* __restrict__ dstH,
    short* __restrict__ dstL, int rows, int cols) {
  __shared__ float tile[32][33];
  int c0 = blockIdx.x * 32, r0 = blockIdx.y * 32;
  int tx = threadIdx.x & 31, ty = threadIdx.x >> 5;
#pragma unroll
  for (int i = 0; i < 32; i += 8)
    tile[ty + i][tx] = src[(size_t)(r0 + ty + i) * cols + c0 + tx];
  __syncthreads();
#pragma unroll
  for (int i = 0; i < 32; i += 8) {
    float v = tile[tx][ty + i];
    short h = f2bh(v);
    size_t di = (size_t)(c0 + ty + i) * rows + r0 + tx;
    dstH[di] = h;
    dstL[di] = f2bh(v - bh2f(h));
  }
}

// ---------------------------------------------------------------------------
// GEMM1: unchanged R10 version (128x128, single-buffer, swizzle, setprio,
// MFMA logits epilogue).
// ---------------------------------------------------------------------------
template <bool ABF>
__global__ __launch_bounds__(256) void k_gemm1(
    const short* __restrict__ xbf, const float* __restrict__ xf,
    const short* __restrict__ W1T, const float* __restrict__ b1,
    const float* __restrict__ W2, float* __restrict__ part) {
  __shared__ __align__(16) char smem[39168];

  const int tid = threadIdx.x;
  const int lane = tid & 63, wave = tid >> 6;
  const int wr = wave >> 1, wc = wave & 1;
  const int fr = lane & 15, fg = lane >> 4;
  const int bx = ((blockIdx.x & 7) << 5) | (blockIdx.x >> 3);  // T1, 256=8*32
  const int m0 = bx * 128, n0 = blockIdx.y * 128;
  const int by = blockIdx.y;

  const int r0 = wave * 16 + (lane >> 2);
  const int lsw = (((lane & 3) ^ ((lane >> 3) & 3)) << 3);
  const short* b0p = W1T + (size_t)(n0 + r0) * HD + lsw;
  const short* b1p = W1T + (size_t)(n0 + r0 + 64) * HD + lsw;

  const short* a0p = nullptr; const short* a1p = nullptr;
  const float* aF = nullptr;
  int ar = 0, ah = 0, p0e = 0, p1e = 0;
  if constexpr (ABF) {
    a0p = xbf + (size_t)(m0 + r0) * HD + lsw;
    a1p = xbf + (size_t)(m0 + r0 + 64) * HD + lsw;
  } else {
    ar = tid >> 1; ah = tid & 1;
    aF = xf + (size_t)(m0 + ar) * HD + ah * 16;
    int s = (ar >> 1) & 3;
    p0e = ((2 * ah) ^ s) << 3;
    p1e = p0e ^ 8;
  }

  f32x4 acc[4][4];
#pragma unroll
  for (int i = 0; i < 4; ++i)
#pragma unroll
    for (int j = 0; j < 4; ++j) acc[i][j] = (f32x4){0.f, 0.f, 0.f, 0.f};

  const int csw = (fr >> 1) & 3;
  for (int k0 = 0; k0 < HD; k0 += 32) {
    gl16(smem + 8192 + wave * 1024, b0p + k0);
    gl16(smem + 12288 + wave * 1024, b1p + k0);
    if constexpr (ABF) {
      gl16(smem + wave * 1024, a0p + k0);
      gl16(smem + 4096 + wave * 1024, a1p + k0);
    } else {
      f32x4 u0 = *(const f32x4*)(aF + k0);
      f32x4 u1 = *(const f32x4*)(aF + k0 + 4);
      f32x4 u2 = *(const f32x4*)(aF + k0 + 8);
      f32x4 u3 = *(const f32x4*)(aF + k0 + 12);
      short8 s0, s1;
#pragma unroll
      for (int q = 0; q < 4; ++q) {
        s0[q] = f2bh(u0[q]); s0[4 + q] = f2bh(u1[q]);
        s1[q] = f2bh(u2[q]); s1[4 + q] = f2bh(u3[q]);
      }
      short* As = (short*)smem;
      *(short8*)(As + ar * 32 + p0e) = s0;
      *(short8*)(As + ar * 32 + p1e) = s1;
    }
    __syncthreads();
    {
      const short* As = (const short*)smem;
      const short* Bs = (const short*)(smem + 8192);
      short8 af[4], bf4[4];
#pragma unroll
      for (int i = 0; i < 4; ++i) {
        af[i]  = *(const short8*)(As + (wr * 64 + i * 16 + fr) * 32 + ((fg ^ csw) << 3));
        bf4[i] = *(const short8*)(Bs + (wc * 64 + i * 16 + fr) * 32 + ((fg ^ csw) << 3));
      }
      __builtin_amdgcn_s_setprio(1);
#pragma unroll
      for (int i = 0; i < 4; ++i)
#pragma unroll
        for (int j = 0; j < 4; ++j)
          acc[i][j] = __builtin_amdgcn_mfma_f32_16x16x32_bf16(af[i], bf4[j], acc[i][j], 0, 0, 0);
      __builtin_amdgcn_s_setprio(0);
    }
    __syncthreads();
  }

  short* hbf = (short*)smem;            // [128][136] bf16
  short* W2b = (short*)(smem + 34816);  // [16][136]
  float b1j[4];
#pragma unroll
  for (int j = 0; j < 4; ++j) b1j[j] = b1[n0 + wc * 64 + j * 16 + fr];
  for (int q = tid; q < 2048; q += 256) {
    int col = q >> 7, k = q & 127;
    W2b[col * 136 + k] = (col < 8) ? f2bh(W2[(size_t)(n0 + k) * 8 + col]) : (short)0;
  }
#pragma unroll
  for (int i = 0; i < 4; ++i)
#pragma unroll
    for (int j = 0; j < 4; ++j) {
      int col = wc * 64 + j * 16 + fr;
#pragma unroll
      for (int q = 0; q < 4; ++q)
        hbf[(wr * 64 + i * 16 + fg * 4 + q) * 136 + col] =
            f2bh(fmaxf(acc[i][j][q] + b1j[j], 0.f));
    }
  __syncthreads();
#pragma unroll
  for (int rg = 0; rg < 2; ++rg) {
    int row16 = wave * 32 + rg * 16;
    f32x4 accl = (f32x4){0.f, 0.f, 0.f, 0.f};
#pragma unroll
    for (int kk = 0; kk < 4; ++kk) {
      short8 a = *(const short8*)(hbf + (row16 + fr) * 136 + kk * 32 + fg * 8);
      short8 b = *(const short8*)(W2b + fr * 136 + kk * 32 + fg * 8);
      accl = __builtin_amdgcn_mfma_f32_16x16x32_bf16(a, b, accl, 0, 0, 0);
    }
    if (fr < 8) {
      float* pp = part + (size_t)(m0 + row16 + fg * 4) * 32 + by * 8 + fr;
#pragma unroll
      for (int q = 0; q < 4; ++q) pp[(size_t)q * 32] = accl[q];
    }
  }
}

// ---------------------------------------------------------------------------
__global__ __launch_bounds__(256) void k_combine(
    const float* __restrict__ part, const float* __restrict__ b2,
    int* __restrict__ sel, int* __restrict__ flagged, int* __restrict__ nflag) {
  int t = blockIdx.x * 256 + threadIdx.x;
  const float* p = part + (size_t)t * 32;
  float lg[8];
#pragma unroll
  for (int e = 0; e < 8; ++e) lg[e] = p[e] + p[8 + e] + p[16 + e] + p[24 + e] + b2[e];
  int be = 0; float best = lg[0];
#pragma unroll
  for (int e = 1; e < 8; ++e) if (lg[e] > best) { best = lg[e]; be = e; }
  float second = -3.4e38f;
#pragma unroll
  for (int e = 0; e < 8; ++e) if (e != be && lg[e] > second) second = lg[e];
  sel[t] = be;
  if (best - second < TAU) {
    int ix = atomicAdd(nflag, 1);
    if (ix < NTOK) flagged[ix] = t;
  }
}

// ---------------------------------------------------------------------------
// Tier-A: bf16x3 re-GEMM of flagged tokens (unchanged).
// ---------------------------------------------------------------------------
__global__ __launch_bounds__(256) void k_gemmR(
    const float* __restrict__ x, const short* __restrict__ W1hT,
    const short* __restrict__ W1lT, const float* __restrict__ b1,
    const float* __restrict__ W2, const int* __restrict__ flagged,
    const int* __restrict__ nflag, float* __restrict__ partR) {
  __shared__ __align__(16) char smem[37888];
  __shared__ int toks[128];
  short* Ah = (short*)smem;
  short* Al = (short*)(smem + 8192);

  int nf = *nflag; if (nf > NTOK) nf = NTOK;
  const int m0 = blockIdx.x * 128;
  if (m0 >= nf) return;
  const int tid = threadIdx.x;
  if (tid < 128) {
    int s = m0 + tid;
    toks[tid] = flagged[s < nf ? s : nf - 1];
  }
  __syncthreads();

  const int lane = tid & 63, wave = tid >> 6;
  const int wr = wave >> 1, wc = wave & 1;
  const int fr = lane & 15, fg = lane >> 4;
  const int n0 = blockIdx.y * 128;
  const int by = blockIdx.y;

  const int off0 = wave * 1024 + lane * 16;
  const int off1 = off0 + 4096;
  const int r0 = off0 >> 6, c0 = (off0 & 63) >> 1;
  const int r1 = off1 >> 6, c1 = (off1 & 63) >> 1;
  const short* bh0p = W1hT + (size_t)(n0 + r0) * HD + c0;
  const short* bh1p = W1hT + (size_t)(n0 + r1) * HD + c1;
  const short* bl0p = W1lT + (size_t)(n0 + r0) * HD + c0;
  const short* bl1p = W1lT + (size_t)(n0 + r1) * HD + c1;
  char* ldsBh0 = smem + 16384 + wave * 1024;
  char* ldsBh1 = smem + 16384 + wave * 1024 + 4096;
  char* ldsBl0 = smem + 24576 + wave * 1024;
  char* ldsBl1 = smem + 24576 + wave * 1024 + 4096;
  const int ar = tid >> 1, ah2 = tid & 1;
  const float* aF = x + (size_t)toks[ar] * HD + ah2 * 16;

  f32x4 acc[4][4];
#pragma unroll
  for (int i = 0; i < 4; ++i)
#pragma unroll
    for (int j = 0; j < 4; ++j) acc[i][j] = (f32x4){0.f, 0.f, 0.f, 0.f};

  for (int k0 = 0; k0 < HD; k0 += 32) {
    gl16(ldsBh0, bh0p + k0);
    gl16(ldsBh1, bh1p + k0);
    gl16(ldsBl0, bl0p + k0);
    gl16(ldsBl1, bl1p + k0);
    f32x4 u0 = *(const f32x4*)(aF + k0);
    f32x4 u1 = *(const f32x4*)(aF + k0 + 4);
    f32x4 u2 = *(const f32x4*)(aF + k0 + 8);
    f32x4 u3 = *(const f32x4*)(aF + k0 + 12);
    short8 sh0, sh1, sl0, sl1;
#pragma unroll
    for (int q = 0; q < 4; ++q) {
      { float f = u0[q]; short h = f2bh(f); sh0[q]     = h; sl0[q]     = f2bh(f - bh2f(h)); }
      { float f = u1[q]; short h = f2bh(f); sh0[4 + q] = h; sl0[4 + q] = f2bh(f - bh2f(h)); }
      { float f = u2[q]; short h = f2bh(f); sh1[q]     = h; sl1[q]     = f2bh(f - bh2f(h)); }
      { float f = u3[q]; short h = f2bh(f); sh1[4 + q] = h; sl1[4 + q] = f2bh(f - bh2f(h)); }
    }
    *(short8*)(Ah + ar * 32 + ah2 * 16)     = sh0;
    *(short8*)(Ah + ar * 32 + ah2 * 16 + 8) = sh1;
    *(short8*)(Al + ar * 32 + ah2 * 16)     = sl0;
    *(short8*)(Al + ar * 32 + ah2 * 16 + 8) = sl1;
    __syncthreads();
    short8 af[4], alf[4], bf[4], blf[4];
#pragma unroll
    for (int i = 0; i < 4; ++i) {
      int row = (wr * 64 + i * 16 + fr) * 32 + fg * 8;
      af[i]  = *(const short8*)(Ah + row);
      alf[i] = *(const short8*)(Al + row);
      int rowb = (wc * 64 + i * 16 + fr) * 32 + fg * 8;
      bf[i]  = *(const short8*)((short*)(smem + 16384) + rowb);
      blf[i] = *(const short8*)((short*)(smem + 24576) + rowb);
    }
#pragma unroll
    for (int i = 0; i < 4; ++i)
#pragma unroll
      for (int j = 0; j < 4; ++j) {
        acc[i][j] = __builtin_amdgcn_mfma_f32_16x16x32_bf16(af[i],  bf[j],  acc[i][j], 0, 0, 0);
        acc[i][j] = __builtin_amdgcn_mfma_f32_16x16x32_bf16(af[i],  blf[j], acc[i][j], 0, 0, 0);
        acc[i][j] = __builtin_amdgcn_mfma_f32_16x16x32_bf16(alf[i], bf[j],  acc[i][j], 0, 0, 0);
      }
    __syncthreads();
  }

  float* hl64 = (float*)smem;            // [64][129]
  float* W2c  = (float*)(smem + 33024);  // [128][8]
  *(f32x4*)(W2c + tid * 4) = *(const f32x4*)(W2 + (size_t)n0 * NEXP + tid * 4);
  float b1j[4];
#pragma unroll
  for (int j = 0; j < 4; ++j) b1j[j] = b1[n0 + wc * 64 + j * 16 + fr];

  for (int p = 0; p < 2; ++p) {
    if (wr == p) {
#pragma unroll
      for (int i = 0; i < 4; ++i)
#pragma unroll
        for (int j = 0; j < 4; ++j) {
          int col = wc * 64 + j * 16 + fr;
#pragma unroll
          for (int q = 0; q < 4; ++q)
            hl64[(i * 16 + fg * 4 + q) * 129 + col] = fmaxf(acc[i][j][q] + b1j[j], 0.f);
        }
    }
    __syncthreads();
    if (tid < 128) {
      int r2 = tid & 63, eh = tid >> 6;
      const float* hrow = hl64 + r2 * 129;
      const float* wcp = W2c + eh * 4;
      float s0 = 0.f, s1 = 0.f, s2 = 0.f, s3 = 0.f;
      for (int f = 0; f < 128; ++f) {
        float hv = hrow[f];
        s0 += hv * wcp[f * 8 + 0];
        s1 += hv * wcp[f * 8 + 1];
        s2 += hv * wcp[f * 8 + 2];
        s3 += hv * wcp[f * 8 + 3];
      }
      float* pp = partR + (size_t)(m0 + p * 64 + r2) * 32 + by * 8 + eh * 4;
      pp[0] = s0; pp[1] = s1; pp[2] = s2; pp[3] = s3;
    }
    __syncthreads();
  }
}

// ---------------------------------------------------------------------------
__global__ __launch_bounds__(256) void k_combineR(
    const float* __restrict__ partR, const float* __restrict__ b2,
    const int* __restrict__ flagged, const int* __restrict__ nflag,
    int* __restrict__ sel, int* __restrict__ flagged2, int* __restrict__ nflag2) {
  int nf = *nflag; if (nf > NTOK) nf = NTOK;
  int s = blockIdx.x * 256 + threadIdx.x;
  if (s >= nf) return;
  int t = flagged[s];
  const float* p = partR + (size_t)s * 32;
  float lg[8];
#pragma unroll
  for (int e = 0; e < 8; ++e) lg[e] = p[e] + p[8 + e] + p[16 + e] + p[24 + e] + b2[e];
  int be = 0; float best = lg[0];
#pragma unroll
  for (int e = 1; e < 8; ++e) if (lg[e] > best) { best = lg[e]; be = e; }
  float second = -3.4e38f;
#pragma unroll
  for (int e = 0; e < 8; ++e) if (e != be && lg[e] > second) second = lg[e];
  sel[t] = be;
  if (best - second < TAU2) {
    int ix = atomicAdd(nflag2, 1);
    if (ix < NTOK) flagged2[ix] = t;
  }
}

// ---------------------------------------------------------------------------
__global__ __launch_bounds__(256) void k_recomputeB(
    const float* __restrict__ x, const float* __restrict__ W1,
    const float* __restrict__ b1, const float* __restrict__ W2,
    const float* __restrict__ b2, const int* __restrict__ flagged2,
    const int* __restrict__ nflag2, int* __restrict__ sel) {
  __shared__ float xs[1024];
  __shared__ double hs[512];
  __shared__ double red[8][32];
  __shared__ double lgd[8];
  int nf = *nflag2; if (nf > NTOK) nf = NTOK;
  const int tid = threadIdx.x;
  for (int ti = blockIdx.x; ti < nf; ti += gridDim.x) {
    int t = flagged2[ti];
    __syncthreads();
    for (int q = tid; q < 1024; q += 256) xs[q] = x[(size_t)t * HD + q];
    __syncthreads();
    int f0 = tid * 2;
    double a0 = 0.0, a1 = 0.0;
    for (int h = 0; h < 1024; h += 4) {
      float2 w0 = *(const float2*)(W1 + (size_t)(h + 0) * FD + f0);
      float2 w1 = *(const float2*)(W1 + (size_t)(h + 1) * FD + f0);
      float2 w2 = *(const float2*)(W1 + (size_t)(h + 2) * FD + f0);
      float2 w3 = *(const float2*)(W1 + (size_t)(h + 3) * FD + f0);
      double x0 = (double)xs[h], x1 = (double)xs[h + 1];
      double x2 = (double)xs[h + 2], x3 = (double)xs[h + 3];
      a0 += x0 * (double)w0.x; a1 += x0 * (double)w0.y;
      a0 += x1 * (double)w1.x; a1 += x1 * (double)w1.y;
      a0 += x2 * (double)w2.x; a1 += x2 * (double)w2.y;
      a0 += x3 * (double)w3.x; a1 += x3 * (double)w3.y;
    }
    a0 += (double)b1[f0]; a1 += (double)b1[f0 + 1];
    hs[f0]     = a0 > 0.0 ? a0 : 0.0;
    hs[f0 + 1] = a1 > 0.0 ? a1 : 0.0;
    __syncthreads();
    {
      int e = tid >> 5, c = tid & 31;
      int fb = c * 16;
      double s = 0.0;
#pragma unroll
      for (int ff = 0; ff < 16; ++ff)
        s += hs[fb + ff] * (double)W2[(size_t)(fb + ff) * 8 + e];
      red[e][c] = s;
    }
    __syncthreads();
    if (tid < 8) {
      double s = 0.0;
#pragma unroll
      for (int c = 0; c < 32; ++c) s += red[tid][c];
      lgd[tid] = s + (double)b2[tid];
    }
    __syncthreads();
    if (tid == 0) {
      int be = 0; double best = lgd[0];
#pragma unroll
      for (int e = 1; e < 8; ++e) if (lgd[e] > best) { best = lgd[e]; be = e; }
      sel[t] = be;
    }
    __syncthreads();
  }
}

// ---------------------------------------------------------------------------
__global__ __launch_bounds__(256) void k_compact(
    const int* __restrict__ sel, int* __restrict__ cnt, int* __restrict__ list) {
  __shared__ int wcnt[4][8];
  __shared__ int woff[4][8];
  __shared__ int bbase[8];
  const int tid = threadIdx.x, lane = tid & 63, wave = tid >> 6;
  const int t = blockIdx.x * 256 + tid;
  const int e = sel[t];
  const unsigned long long ltmask = (1ull << lane) - 1ull;
  int rank = 0;
#pragma unroll
  for (int e2 = 0; e2 < 8; ++e2) {
    unsigned long long m = __ballot(e == e2);
    if (e2 == e) rank = __popcll(m & ltmask);
    if (lane == 0) wcnt[wave][e2] = __popcll(m);
  }
  __syncthreads();
  if (tid < 8) {
    int s0 = wcnt[0][tid], s1 = wcnt[1][tid], s2 = wcnt[2][tid], s3 = wcnt[3][tid];
    woff[0][tid] = 0; woff[1][tid] = s0; woff[2][tid] = s0 + s1; woff[3][tid] = s0 + s1 + s2;
    bbase[tid] = atomicAdd(&cnt[tid], s0 + s1 + s2 + s3);
  }
  __syncthreads();
  list[(size_t)e * NTOK + bbase[e] + woff[wave][e] + rank] = t;
}

__global__ void k_build_desc(const int* __restrict__ cnt, int* __restrict__ desc,
                             int* __restrict__ ntl) {
  if (threadIdx.x == 0 && blockIdx.x == 0) {
    int n = 0;
    for (int e = 0; e < 8; ++e) {
      int m = (cnt[e] + 255) >> 8;   // 256-row tiles for gemm2 v2
      for (int i = 0; i < m; ++i) desc[n++] = (e << 16) | i;
    }
    *ntl = n;
  }
}

// ---------------------------------------------------------------------------
// GEMM2 v2: 256x256 tile, BK=32, 8 waves (512 thr), minimum-2-phase.
// __launch_bounds__(512) — 1 wg/CU, 256 VGPR/wave budget (R11 spilled with
// (512,2): acc[8][4]=128 VGPR alone; WRITE_SIZE showed 4.4 GB scratch).
// ---------------------------------------------------------------------------
template <bool ABF>
__global__ __launch_bounds__(512) void k_gemm2(
    const short* __restrict__ xbf, const float* __restrict__ xf,
    const short* __restrict__ WexpT, const float* __restrict__ expert_b,
    const int* __restrict__ cnt, const int* __restrict__ list,
    const int* __restrict__ desc, const int* __restrict__ ntl,
    float* __restrict__ out) {
  __shared__ __align__(16) char smem[65536];
  // Abuf[2]: [0,16K),[16K,32K). Bbuf[2]: [32K,48K),[48K,64K).
  const int bx = (blockIdx.x % 8) * 17 + blockIdx.x / 8;  // T1 bijective, 136=8*17
  if (bx >= *ntl) return;
  int dsc = desc[bx];
  int e = dsc >> 16, mt = dsc & 0xffff;
  int ce = cnt[e];
  int mb = mt * 256;
  int rows = ce - mb; if (rows > 256) rows = 256;

  const int tid = threadIdx.x;
  const int lane = tid & 63, wave = tid >> 6;
  const int wr = wave >> 2, wcol = wave & 3;      // 2M x 4N wave grid
  const int fr = lane & 15, fg = lane >> 4;
  const int n0 = blockIdx.y * 256;
  const size_t ebase = (size_t)e << 20;
  const int lr = lane >> 2;                                 // 0..15
  const int gc8 = (((lane & 3) ^ ((lane >> 3) & 3)) << 3);  // swizzled src chunk

  const short* bP0 = WexpT + ebase + (size_t)(n0 + wave * 32 + lr) * HD + gc8;
  const short* bP1 = bP0 + (size_t)16 * HD;

  const short* aP0 = nullptr; const short* aP1 = nullptr;
  const float* aF = nullptr;
  int arow = 0, pc0 = 0, pc1 = 0;
  if constexpr (ABF) {
    int r0 = wave * 32 + lr, r1 = r0 + 16;
    int i0 = mb + r0; i0 = i0 < ce ? i0 : ce - 1;
    int i1 = mb + r1; i1 = i1 < ce ? i1 : ce - 1;
    aP0 = xbf + (size_t)list[(size_t)e * NTOK + i0] * HD + gc8;
    aP1 = xbf + (size_t)list[(size_t)e * NTOK + i1] * HD + gc8;
  } else {
    arow = tid >> 1;
    int idx = mb + arow; idx = idx < ce ? idx : ce - 1;
    aF = xf + (size_t)list[(size_t)e * NTOK + idx] * HD + (tid & 1) * 16;
    int c0 = (tid & 1) * 2, s = (arow >> 1) & 3;
    pc0 = (c0 ^ s) << 3; pc1 = ((c0 + 1) ^ s) << 3;
  }

  f32x4 acc[8][4];
#pragma unroll
  for (int i = 0; i < 8; ++i)
#pragma unroll
    for (int j = 0; j < 4; ++j) acc[i][j] = (f32x4){0.f, 0.f, 0.f, 0.f};

  auto STAGE = [&](int kt, int b) {
    const int k0 = kt * 32;
    gl16(smem + 32768 + b * 16384 + wave * 2048,        bP0 + k0);
    gl16(smem + 32768 + b * 16384 + wave * 2048 + 1024, bP1 + k0);
    if constexpr (ABF) {
      gl16(smem + b * 16384 + wave * 2048,        aP0 + k0);
      gl16(smem + b * 16384 + wave * 2048 + 1024, aP1 + k0);
    } else {
      f32x4 u0 = *(const f32x4*)(aF + k0);
      f32x4 u1 = *(const f32x4*)(aF + k0 + 4);
      f32x4 u2 = *(const f32x4*)(aF + k0 + 8);
      f32x4 u3 = *(const f32x4*)(aF + k0 + 12);
      short8 s0, s1;
#pragma unroll
      for (int q = 0; q < 4; ++q) {
        s0[q] = f2bh(u0[q]); s0[4 + q] = f2bh(u1[q]);
        s1[q] = f2bh(u2[q]); s1[4 + q] = f2bh(u3[q]);
      }
      short* As = (short*)(smem + b * 16384);
      *(short8*)(As + arow * 32 + pc0) = s0;
      *(short8*)(As + arow * 32 + pc1) = s1;
    }
  };
  const int csw = (fr >> 1) & 3;
  auto COMPUTE = [&](int b) {
    const short* As = (const short*)(smem + b * 16384);
    const short* Bs = (const short*)(smem + 32768 + b * 16384);
    short8 a[8], bb[4];
#pragma unroll
    for (int i = 0; i < 8; ++i)
      a[i] = *(const short8*)(As + (wr * 128 + i * 16 + fr) * 32 + ((fg ^ csw) << 3));
#pragma unroll
    for (int j = 0; j < 4; ++j)
      bb[j] = *(const short8*)(Bs + (wcol * 64 + j * 16 + fr) * 32 + ((fg ^ csw) << 3));
    __builtin_amdgcn_s_setprio(1);
#pragma unroll
    for (int i = 0; i < 8; ++i)
#pragma unroll
      for (int j = 0; j < 4; ++j)
        acc[i][j] = __builtin_amdgcn_mfma_f32_16x16x32_bf16(a[i], bb[j], acc[i][j], 0, 0, 0);
    __builtin_amdgcn_s_setprio(0);
  };

  STAGE(0, 0);
  __syncthreads();
  int cur = 0;
#pragma unroll 1
  for (int kt = 0; kt < 32; ++kt) {
    if (kt + 1 < 32) STAGE(kt + 1, cur ^ 1);
    COMPUTE(cur);
    __syncthreads();
    cur ^= 1;
  }

  // Coalesced epilogue: 16 passes of 16 rows via [16][264] f32 LDS buffer.
  float ebv[4];
#pragma unroll
  for (int j = 0; j < 4; ++j)
    ebv[j] = expert_b[e * HD + n0 + wcol * 64 + j * 16 + fr];
  float* buf = (float*)smem;  // 16*264*4 = 16896 B
  const int row16 = tid >> 5, cc = tid & 31;
  const int listbase = (int)((size_t)e * NTOK) + mb;
#pragma unroll 1
  for (int p = 0; p < 16; ++p) {
    if (wr == (p >> 3)) {
      const int i = p & 7;
#pragma unroll
      for (int j = 0; j < 4; ++j) {
        int col = wcol * 64 + j * 16 + fr;
#pragma unroll
        for (int q = 0; q < 4; ++q)
          buf[(fg * 4 + q) * 264 + col] = acc[i][j][q] + ebv[j];
      }
    }
    __syncthreads();
    const int rr = p * 16 + row16;
    if (rr < rows) {
      int tok = list[listbase + rr];
      float* op = out + (size_t)tok * HD + n0 + cc * 8;
      *(f32x4*)op       = *(const f32x4*)(buf + row16 * 264 + cc * 8);
      *(f32x4*)(op + 4) = *(const f32x4*)(buf + row16 * 264 + cc * 8 + 4);
    }
    __syncthreads();
  }
}

// ---------------------------------------------------------------------------
extern "C" void kernel_launch(void* const* d_in, const int* in_sizes, int n_in,
                              void* d_out, int out_size, void* d_ws, size_t ws_size,
                              hipStream_t stream) {
  const float* x  = (const float*)d_in[0];
  const float* W1 = (const float*)d_in[1];
  const float* b1 = (const float*)d_in[2];
  const float* W2 = (const float*)d_in[3];
  const float* b2 = (const float*)d_in[4];
  const float* eW = (const float*)d_in[5];
  const float* eb = (const float*)d_in[6];
  float* out = (float*)d_out;
  char* ws = (char*)d_ws;

  const size_t XBF_BYTES = (size_t)NTOK * HD * 2;  // 67,108,864
  size_t need_rest = 16777216ull + 1048576 + 4194304 + 131072 * 3 + 1048576 + 4096;
  bool big = ws_size >= XBF_BYTES + need_rest;

  size_t off = 0;
  short* xbf = nullptr;
  if (big) { xbf = (short*)ws; off += XBF_BYTES; }
  short* WexpT  = (short*)(ws + off); off += 16777216;
  short* W1T    = (short*)(ws + off); off += 1048576;
  float* part   = (float*)(ws + off); off += 4194304;   // also partR (tier-A)
  int* sel      = (int*)(ws + off); off += 131072;
  int* flagged  = (int*)(ws + off); off += 131072;
  int* flagged2 = (int*)(ws + off); off += 131072;
  int* list     = (int*)(ws + off); off += 1048576;     // also W1lT before compact
  int* cnt      = (int*)(ws + off); off += 32;
  int* nflag    = (int*)(ws + off); off += 4;
  int* ntl      = (int*)(ws + off); off += 4;
  int* nflag2   = (int*)(ws + off); off += 24;
  int* desc     = (int*)(ws + off); off += 1088;
  if (ws_size < off) return;

  short* W1lT = (short*)list;  // 1 MB, live until k_compact

  hipMemsetAsync(cnt, 0, 44, stream);  // cnt[8], nflag, ntl, nflag2

  dim3 b256(256), b512(512);
  if (big) k_convert<<<dim3(16384), b256, 0, stream>>>(x, xbf);
  k_transpose_split<<<dim3(16, 32), b256, 0, stream>>>(W1, W1T, W1lT, 1024, 512);
  k_transpose<<<dim3(32, 32, 8), b256, 0, stream>>>(eW, WexpT, 1024, 1024);
  if (big)
    k_gemm1<true><<<dim3(256, 4), b256, 0, stream>>>(xbf, nullptr, W1T, b1, W2, part);
  else
    k_gemm1<false><<<dim3(256, 4), b256, 0, stream>>>(nullptr, x, W1T, b1, W2, part);
  k_combine<<<dim3(128), b256, 0, stream>>>(part, b2, sel, flagged, nflag);
  k_gemmR<<<dim3(256, 4), b256, 0, stream>>>(x, W1T, W1lT, b1, W2, flagged, nflag, part);
  k_combineR<<<dim3(128), b256, 0, stream>>>(part, b2, flagged, nflag, sel, flagged2, nflag2);
  k_recomputeB<<<dim3(128), b256, 0, stream>>>(x, W1, b1, W2, b2, flagged2, nflag2, sel);
  k_compact<<<dim3(128), b256, 0, stream>>>(sel, cnt, list);
  k_build_desc<<<dim3(1), dim3(64), 0, stream>>>(cnt, desc, ntl);
  if (big)
    k_gemm2<true><<<dim3(136, 4), b512, 0, stream>>>(xbf, nullptr, WexpT, eb, cnt, list, desc, ntl, out);
  else
    k_gemm2<false><<<dim3(136, 4), b512, 0, stream>>>(nullptr, x, WexpT, eb, cnt, list, desc, ntl, out);
}

// Round 13
// 362.409 us; speedup vs baseline: 3.2955x; 3.2937x over previous
//
#include <hip/hip_runtime.h>
#include <hip/hip_bf16.h>
#include <stdint.h>

#define NTOK 32768
#define HD 1024
#define FD 512
#define NEXP 8
#define TAU 0.05f
#define TAU2 4e-4f

typedef __attribute__((ext_vector_type(8))) short short8;
typedef __attribute__((ext_vector_type(4))) float f32x4;

__device__ __forceinline__ short f2bh(float f) {
  uint32_t u = __float_as_uint(f);
  return (short)((u + 0x7fffu + ((u >> 16) & 1u)) >> 16);
}
__device__ __forceinline__ float bh2f(short h) {
  return __uint_as_float(((uint32_t)(uint16_t)h) << 16);
}

__device__ __forceinline__ void gl16(void* lds, const void* g) {
  __builtin_amdgcn_global_load_lds(
      (const __attribute__((address_space(1))) void*)g,
      (__attribute__((address_space(3))) void*)lds, 16, 0, 0);
}

// ---------------------------------------------------------------------------
__global__ __launch_bounds__(256) void k_convert(const float* __restrict__ x,
                                                 short* __restrict__ xbf) {
  size_t i = ((size_t)blockIdx.x * 256 + threadIdx.x) * 8;
  f32x4 v0 = *(const f32x4*)(x + i);
  f32x4 v1 = *(const f32x4*)(x + i + 4);
  short8 o;
#pragma unroll
  for (int q = 0; q < 4; ++q) { o[q] = f2bh(v0[q]); o[4 + q] = f2bh(v1[q]); }
  *(short8*)(xbf + i) = o;
}

// ---------------------------------------------------------------------------
__global__ __launch_bounds__(256) void k_transpose(
    const float* __restrict__ src, short* __restrict__ dst, int rows, int cols) {
  __shared__ float tile[32][33];
  size_t msz = (size_t)rows * cols;
  src += (size_t)blockIdx.z * msz;
  dst += (size_t)blockIdx.z * msz;
  int c0 = blockIdx.x * 32, r0 = blockIdx.y * 32;
  int tx = threadIdx.x & 31, ty = threadIdx.x >> 5;
#pragma unroll
  for (int i = 0; i < 32; i += 8)
    tile[ty + i][tx] = src[(size_t)(r0 + ty + i) * cols + c0 + tx];
  __syncthreads();
#pragma unroll
  for (int i = 0; i < 32; i += 8)
    dst[(size_t)(c0 + ty + i) * rows + r0 + tx] = f2bh(tile[tx][ty + i]);
}

// ---------------------------------------------------------------------------
__global__ __launch_bounds__(256) void k_transpose_split(
    const float* __restrict__ src, short* __restrict__ dstH,
    short* __restrict__ dstL, int rows, int cols) {
  __shared__ float tile[32][33];
  int c0 = blockIdx.x * 32, r0 = blockIdx.y * 32;
  int tx = threadIdx.x & 31, ty = threadIdx.x >> 5;
#pragma unroll
  for (int i = 0; i < 32; i += 8)
    tile[ty + i][tx] = src[(size_t)(r0 + ty + i) * cols + c0 + tx];
  __syncthreads();
#pragma unroll
  for (int i = 0; i < 32; i += 8) {
    float v = tile[tx][ty + i];
    short h = f2bh(v);
    size_t di = (size_t)(c0 + ty + i) * rows + r0 + tx;
    dstH[di] = h;
    dstL[di] = f2bh(v - bh2f(h));
  }
}

// ---------------------------------------------------------------------------
// GEMM1: unchanged R10 version (128x128, single-buffer, swizzle, setprio,
// MFMA logits epilogue).
// ---------------------------------------------------------------------------
template <bool ABF>
__global__ __launch_bounds__(256) void k_gemm1(
    const short* __restrict__ xbf, const float* __restrict__ xf,
    const short* __restrict__ W1T, const float* __restrict__ b1,
    const float* __restrict__ W2, float* __restrict__ part) {
  __shared__ __align__(16) char smem[39168];

  const int tid = threadIdx.x;
  const int lane = tid & 63, wave = tid >> 6;
  const int wr = wave >> 1, wc = wave & 1;
  const int fr = lane & 15, fg = lane >> 4;
  const int bx = ((blockIdx.x & 7) << 5) | (blockIdx.x >> 3);  // T1, 256=8*32
  const int m0 = bx * 128, n0 = blockIdx.y * 128;
  const int by = blockIdx.y;

  const int r0 = wave * 16 + (lane >> 2);
  const int lsw = (((lane & 3) ^ ((lane >> 3) & 3)) << 3);
  const short* b0p = W1T + (size_t)(n0 + r0) * HD + lsw;
  const short* b1p = W1T + (size_t)(n0 + r0 + 64) * HD + lsw;

  const short* a0p = nullptr; const short* a1p = nullptr;
  const float* aF = nullptr;
  int ar = 0, ah = 0, p0e = 0, p1e = 0;
  if constexpr (ABF) {
    a0p = xbf + (size_t)(m0 + r0) * HD + lsw;
    a1p = xbf + (size_t)(m0 + r0 + 64) * HD + lsw;
  } else {
    ar = tid >> 1; ah = tid & 1;
    aF = xf + (size_t)(m0 + ar) * HD + ah * 16;
    int s = (ar >> 1) & 3;
    p0e = ((2 * ah) ^ s) << 3;
    p1e = p0e ^ 8;
  }

  f32x4 acc[4][4];
#pragma unroll
  for (int i = 0; i < 4; ++i)
#pragma unroll
    for (int j = 0; j < 4; ++j) acc[i][j] = (f32x4){0.f, 0.f, 0.f, 0.f};

  const int csw = (fr >> 1) & 3;
  for (int k0 = 0; k0 < HD; k0 += 32) {
    gl16(smem + 8192 + wave * 1024, b0p + k0);
    gl16(smem + 12288 + wave * 1024, b1p + k0);
    if constexpr (ABF) {
      gl16(smem + wave * 1024, a0p + k0);
      gl16(smem + 4096 + wave * 1024, a1p + k0);
    } else {
      f32x4 u0 = *(const f32x4*)(aF + k0);
      f32x4 u1 = *(const f32x4*)(aF + k0 + 4);
      f32x4 u2 = *(const f32x4*)(aF + k0 + 8);
      f32x4 u3 = *(const f32x4*)(aF + k0 + 12);
      short8 s0, s1;
#pragma unroll
      for (int q = 0; q < 4; ++q) {
        s0[q] = f2bh(u0[q]); s0[4 + q] = f2bh(u1[q]);
        s1[q] = f2bh(u2[q]); s1[4 + q] = f2bh(u3[q]);
      }
      short* As = (short*)smem;
      *(short8*)(As + ar * 32 + p0e) = s0;
      *(short8*)(As + ar * 32 + p1e) = s1;
    }
    __syncthreads();
    {
      const short* As = (const short*)smem;
      const short* Bs = (const short*)(smem + 8192);
      short8 af[4], bf4[4];
#pragma unroll
      for (int i = 0; i < 4; ++i) {
        af[i]  = *(const short8*)(As + (wr * 64 + i * 16 + fr) * 32 + ((fg ^ csw) << 3));
        bf4[i] = *(const short8*)(Bs + (wc * 64 + i * 16 + fr) * 32 + ((fg ^ csw) << 3));
      }
      __builtin_amdgcn_s_setprio(1);
#pragma unroll
      for (int i = 0; i < 4; ++i)
#pragma unroll
        for (int j = 0; j < 4; ++j)
          acc[i][j] = __builtin_amdgcn_mfma_f32_16x16x32_bf16(af[i], bf4[j], acc[i][j], 0, 0, 0);
      __builtin_amdgcn_s_setprio(0);
    }
    __syncthreads();
  }

  short* hbf = (short*)smem;            // [128][136] bf16
  short* W2b = (short*)(smem + 34816);  // [16][136]
  float b1j[4];
#pragma unroll
  for (int j = 0; j < 4; ++j) b1j[j] = b1[n0 + wc * 64 + j * 16 + fr];
  for (int q = tid; q < 2048; q += 256) {
    int col = q >> 7, k = q & 127;
    W2b[col * 136 + k] = (col < 8) ? f2bh(W2[(size_t)(n0 + k) * 8 + col]) : (short)0;
  }
#pragma unroll
  for (int i = 0; i < 4; ++i)
#pragma unroll
    for (int j = 0; j < 4; ++j) {
      int col = wc * 64 + j * 16 + fr;
#pragma unroll
      for (int q = 0; q < 4; ++q)
        hbf[(wr * 64 + i * 16 + fg * 4 + q) * 136 + col] =
            f2bh(fmaxf(acc[i][j][q] + b1j[j], 0.f));
    }
  __syncthreads();
#pragma unroll
  for (int rg = 0; rg < 2; ++rg) {
    int row16 = wave * 32 + rg * 16;
    f32x4 accl = (f32x4){0.f, 0.f, 0.f, 0.f};
#pragma unroll
    for (int kk = 0; kk < 4; ++kk) {
      short8 a = *(const short8*)(hbf + (row16 + fr) * 136 + kk * 32 + fg * 8);
      short8 b = *(const short8*)(W2b + fr * 136 + kk * 32 + fg * 8);
      accl = __builtin_amdgcn_mfma_f32_16x16x32_bf16(a, b, accl, 0, 0, 0);
    }
    if (fr < 8) {
      float* pp = part + (size_t)(m0 + row16 + fg * 4) * 32 + by * 8 + fr;
#pragma unroll
      for (int q = 0; q < 4; ++q) pp[(size_t)q * 32] = accl[q];
    }
  }
}

// ---------------------------------------------------------------------------
__global__ __launch_bounds__(256) void k_combine(
    const float* __restrict__ part, const float* __restrict__ b2,
    int* __restrict__ sel, int* __restrict__ flagged, int* __restrict__ nflag) {
  int t = blockIdx.x * 256 + threadIdx.x;
  const float* p = part + (size_t)t * 32;
  float lg[8];
#pragma unroll
  for (int e = 0; e < 8; ++e) lg[e] = p[e] + p[8 + e] + p[16 + e] + p[24 + e] + b2[e];
  int be = 0; float best = lg[0];
#pragma unroll
  for (int e = 1; e < 8; ++e) if (lg[e] > best) { best = lg[e]; be = e; }
  float second = -3.4e38f;
#pragma unroll
  for (int e = 0; e < 8; ++e) if (e != be && lg[e] > second) second = lg[e];
  sel[t] = be;
  if (best - second < TAU) {
    int ix = atomicAdd(nflag, 1);
    if (ix < NTOK) flagged[ix] = t;
  }
}

// ---------------------------------------------------------------------------
// Tier-A: bf16x3 re-GEMM of flagged tokens (unchanged).
// ---------------------------------------------------------------------------
__global__ __launch_bounds__(256) void k_gemmR(
    const float* __restrict__ x, const short* __restrict__ W1hT,
    const short* __restrict__ W1lT, const float* __restrict__ b1,
    const float* __restrict__ W2, const int* __restrict__ flagged,
    const int* __restrict__ nflag, float* __restrict__ partR) {
  __shared__ __align__(16) char smem[37888];
  __shared__ int toks[128];
  short* Ah = (short*)smem;
  short* Al = (short*)(smem + 8192);

  int nf = *nflag; if (nf > NTOK) nf = NTOK;
  const int m0 = blockIdx.x * 128;
  if (m0 >= nf) return;
  const int tid = threadIdx.x;
  if (tid < 128) {
    int s = m0 + tid;
    toks[tid] = flagged[s < nf ? s : nf - 1];
  }
  __syncthreads();

  const int lane = tid & 63, wave = tid >> 6;
  const int wr = wave >> 1, wc = wave & 1;
  const int fr = lane & 15, fg = lane >> 4;
  const int n0 = blockIdx.y * 128;
  const int by = blockIdx.y;

  const int off0 = wave * 1024 + lane * 16;
  const int off1 = off0 + 4096;
  const int r0 = off0 >> 6, c0 = (off0 & 63) >> 1;
  const int r1 = off1 >> 6, c1 = (off1 & 63) >> 1;
  const short* bh0p = W1hT + (size_t)(n0 + r0) * HD + c0;
  const short* bh1p = W1hT + (size_t)(n0 + r1) * HD + c1;
  const short* bl0p = W1lT + (size_t)(n0 + r0) * HD + c0;
  const short* bl1p = W1lT + (size_t)(n0 + r1) * HD + c1;
  char* ldsBh0 = smem + 16384 + wave * 1024;
  char* ldsBh1 = smem + 16384 + wave * 1024 + 4096;
  char* ldsBl0 = smem + 24576 + wave * 1024;
  char* ldsBl1 = smem + 24576 + wave * 1024 + 4096;
  const int ar = tid >> 1, ah2 = tid & 1;
  const float* aF = x + (size_t)toks[ar] * HD + ah2 * 16;

  f32x4 acc[4][4];
#pragma unroll
  for (int i = 0; i < 4; ++i)
#pragma unroll
    for (int j = 0; j < 4; ++j) acc[i][j] = (f32x4){0.f, 0.f, 0.f, 0.f};

  for (int k0 = 0; k0 < HD; k0 += 32) {
    gl16(ldsBh0, bh0p + k0);
    gl16(ldsBh1, bh1p + k0);
    gl16(ldsBl0, bl0p + k0);
    gl16(ldsBl1, bl1p + k0);
    f32x4 u0 = *(const f32x4*)(aF + k0);
    f32x4 u1 = *(const f32x4*)(aF + k0 + 4);
    f32x4 u2 = *(const f32x4*)(aF + k0 + 8);
    f32x4 u3 = *(const f32x4*)(aF + k0 + 12);
    short8 sh0, sh1, sl0, sl1;
#pragma unroll
    for (int q = 0; q < 4; ++q) {
      { float f = u0[q]; short h = f2bh(f); sh0[q]     = h; sl0[q]     = f2bh(f - bh2f(h)); }
      { float f = u1[q]; short h = f2bh(f); sh0[4 + q] = h; sl0[4 + q] = f2bh(f - bh2f(h)); }
      { float f = u2[q]; short h = f2bh(f); sh1[q]     = h; sl1[q]     = f2bh(f - bh2f(h)); }
      { float f = u3[q]; short h = f2bh(f); sh1[4 + q] = h; sl1[4 + q] = f2bh(f - bh2f(h)); }
    }
    *(short8*)(Ah + ar * 32 + ah2 * 16)     = sh0;
    *(short8*)(Ah + ar * 32 + ah2 * 16 + 8) = sh1;
    *(short8*)(Al + ar * 32 + ah2 * 16)     = sl0;
    *(short8*)(Al + ar * 32 + ah2 * 16 + 8) = sl1;
    __syncthreads();
    short8 af[4], alf[4], bf[4], blf[4];
#pragma unroll
    for (int i = 0; i < 4; ++i) {
      int row = (wr * 64 + i * 16 + fr) * 32 + fg * 8;
      af[i]  = *(const short8*)(Ah + row);
      alf[i] = *(const short8*)(Al + row);
      int rowb = (wc * 64 + i * 16 + fr) * 32 + fg * 8;
      bf[i]  = *(const short8*)((short*)(smem + 16384) + rowb);
      blf[i] = *(const short8*)((short*)(smem + 24576) + rowb);
    }
#pragma unroll
    for (int i = 0; i < 4; ++i)
#pragma unroll
      for (int j = 0; j < 4; ++j) {
        acc[i][j] = __builtin_amdgcn_mfma_f32_16x16x32_bf16(af[i],  bf[j],  acc[i][j], 0, 0, 0);
        acc[i][j] = __builtin_amdgcn_mfma_f32_16x16x32_bf16(af[i],  blf[j], acc[i][j], 0, 0, 0);
        acc[i][j] = __builtin_amdgcn_mfma_f32_16x16x32_bf16(alf[i], bf[j],  acc[i][j], 0, 0, 0);
      }
    __syncthreads();
  }

  float* hl64 = (float*)smem;            // [64][129]
  float* W2c  = (float*)(smem + 33024);  // [128][8]
  *(f32x4*)(W2c + tid * 4) = *(const f32x4*)(W2 + (size_t)n0 * NEXP + tid * 4);
  float b1j[4];
#pragma unroll
  for (int j = 0; j < 4; ++j) b1j[j] = b1[n0 + wc * 64 + j * 16 + fr];

  for (int p = 0; p < 2; ++p) {
    if (wr == p) {
#pragma unroll
      for (int i = 0; i < 4; ++i)
#pragma unroll
        for (int j = 0; j < 4; ++j) {
          int col = wc * 64 + j * 16 + fr;
#pragma unroll
          for (int q = 0; q < 4; ++q)
            hl64[(i * 16 + fg * 4 + q) * 129 + col] = fmaxf(acc[i][j][q] + b1j[j], 0.f);
        }
    }
    __syncthreads();
    if (tid < 128) {
      int r2 = tid & 63, eh = tid >> 6;
      const float* hrow = hl64 + r2 * 129;
      const float* wcp = W2c + eh * 4;
      float s0 = 0.f, s1 = 0.f, s2 = 0.f, s3 = 0.f;
      for (int f = 0; f < 128; ++f) {
        float hv = hrow[f];
        s0 += hv * wcp[f * 8 + 0];
        s1 += hv * wcp[f * 8 + 1];
        s2 += hv * wcp[f * 8 + 2];
        s3 += hv * wcp[f * 8 + 3];
      }
      float* pp = partR + (size_t)(m0 + p * 64 + r2) * 32 + by * 8 + eh * 4;
      pp[0] = s0; pp[1] = s1; pp[2] = s2; pp[3] = s3;
    }
    __syncthreads();
  }
}

// ---------------------------------------------------------------------------
__global__ __launch_bounds__(256) void k_combineR(
    const float* __restrict__ partR, const float* __restrict__ b2,
    const int* __restrict__ flagged, const int* __restrict__ nflag,
    int* __restrict__ sel, int* __restrict__ flagged2, int* __restrict__ nflag2) {
  int nf = *nflag; if (nf > NTOK) nf = NTOK;
  int s = blockIdx.x * 256 + threadIdx.x;
  if (s >= nf) return;
  int t = flagged[s];
  const float* p = partR + (size_t)s * 32;
  float lg[8];
#pragma unroll
  for (int e = 0; e < 8; ++e) lg[e] = p[e] + p[8 + e] + p[16 + e] + p[24 + e] + b2[e];
  int be = 0; float best = lg[0];
#pragma unroll
  for (int e = 1; e < 8; ++e) if (lg[e] > best) { best = lg[e]; be = e; }
  float second = -3.4e38f;
#pragma unroll
  for (int e = 0; e < 8; ++e) if (e != be && lg[e] > second) second = lg[e];
  sel[t] = be;
  if (best - second < TAU2) {
    int ix = atomicAdd(nflag2, 1);
    if (ix < NTOK) flagged2[ix] = t;
  }
}

// ---------------------------------------------------------------------------
__global__ __launch_bounds__(256) void k_recomputeB(
    const float* __restrict__ x, const float* __restrict__ W1,
    const float* __restrict__ b1, const float* __restrict__ W2,
    const float* __restrict__ b2, const int* __restrict__ flagged2,
    const int* __restrict__ nflag2, int* __restrict__ sel) {
  __shared__ float xs[1024];
  __shared__ double hs[512];
  __shared__ double red[8][32];
  __shared__ double lgd[8];
  int nf = *nflag2; if (nf > NTOK) nf = NTOK;
  const int tid = threadIdx.x;
  for (int ti = blockIdx.x; ti < nf; ti += gridDim.x) {
    int t = flagged2[ti];
    __syncthreads();
    for (int q = tid; q < 1024; q += 256) xs[q] = x[(size_t)t * HD + q];
    __syncthreads();
    int f0 = tid * 2;
    double a0 = 0.0, a1 = 0.0;
    for (int h = 0; h < 1024; h += 4) {
      float2 w0 = *(const float2*)(W1 + (size_t)(h + 0) * FD + f0);
      float2 w1 = *(const float2*)(W1 + (size_t)(h + 1) * FD + f0);
      float2 w2 = *(const float2*)(W1 + (size_t)(h + 2) * FD + f0);
      float2 w3 = *(const float2*)(W1 + (size_t)(h + 3) * FD + f0);
      double x0 = (double)xs[h], x1 = (double)xs[h + 1];
      double x2 = (double)xs[h + 2], x3 = (double)xs[h + 3];
      a0 += x0 * (double)w0.x; a1 += x0 * (double)w0.y;
      a0 += x1 * (double)w1.x; a1 += x1 * (double)w1.y;
      a0 += x2 * (double)w2.x; a1 += x2 * (double)w2.y;
      a0 += x3 * (double)w3.x; a1 += x3 * (double)w3.y;
    }
    a0 += (double)b1[f0]; a1 += (double)b1[f0 + 1];
    hs[f0]     = a0 > 0.0 ? a0 : 0.0;
    hs[f0 + 1] = a1 > 0.0 ? a1 : 0.0;
    __syncthreads();
    {
      int e = tid >> 5, c = tid & 31;
      int fb = c * 16;
      double s = 0.0;
#pragma unroll
      for (int ff = 0; ff < 16; ++ff)
        s += hs[fb + ff] * (double)W2[(size_t)(fb + ff) * 8 + e];
      red[e][c] = s;
    }
    __syncthreads();
    if (tid < 8) {
      double s = 0.0;
#pragma unroll
      for (int c = 0; c < 32; ++c) s += red[tid][c];
      lgd[tid] = s + (double)b2[tid];
    }
    __syncthreads();
    if (tid == 0) {
      int be = 0; double best = lgd[0];
#pragma unroll
      for (int e = 1; e < 8; ++e) if (lgd[e] > best) { best = lgd[e]; be = e; }
      sel[t] = be;
    }
    __syncthreads();
  }
}

// ---------------------------------------------------------------------------
__global__ __launch_bounds__(256) void k_compact(
    const int* __restrict__ sel, int* __restrict__ cnt, int* __restrict__ list) {
  __shared__ int wcnt[4][8];
  __shared__ int woff[4][8];
  __shared__ int bbase[8];
  const int tid = threadIdx.x, lane = tid & 63, wave = tid >> 6;
  const int t = blockIdx.x * 256 + tid;
  const int e = sel[t];
  const unsigned long long ltmask = (1ull << lane) - 1ull;
  int rank = 0;
#pragma unroll
  for (int e2 = 0; e2 < 8; ++e2) {
    unsigned long long m = __ballot(e == e2);
    if (e2 == e) rank = __popcll(m & ltmask);
    if (lane == 0) wcnt[wave][e2] = __popcll(m);
  }
  __syncthreads();
  if (tid < 8) {
    int s0 = wcnt[0][tid], s1 = wcnt[1][tid], s2 = wcnt[2][tid], s3 = wcnt[3][tid];
    woff[0][tid] = 0; woff[1][tid] = s0; woff[2][tid] = s0 + s1; woff[3][tid] = s0 + s1 + s2;
    bbase[tid] = atomicAdd(&cnt[tid], s0 + s1 + s2 + s3);
  }
  __syncthreads();
  list[(size_t)e * NTOK + bbase[e] + woff[wave][e] + rank] = t;
}

__global__ void k_build_desc(const int* __restrict__ cnt, int* __restrict__ desc,
                             int* __restrict__ ntl) {
  if (threadIdx.x == 0 && blockIdx.x == 0) {
    int n = 0;
    for (int e = 0; e < 8; ++e) {
      int m = (cnt[e] + 255) >> 8;   // 256-row tiles for gemm2 v2
      for (int i = 0; i < m; ++i) desc[n++] = (e << 16) | i;
    }
    *ntl = n;
  }
}

// ---------------------------------------------------------------------------
// GEMM2 v2: 256x256 tile, BK=32, 8 waves, minimum-2-phase. Epilogue pass
// loop FULLY UNROLLED (rule #20: runtime-indexed acc -> scratch; R11/R12's
// "#pragma unroll 1" + acc[p&7] put the accumulator in local memory —
// WRITE_SIZE 4.4 GB of scratch traffic, VGPR=100, MfmaUtil 3%).
// ---------------------------------------------------------------------------
template <bool ABF>
__global__ __launch_bounds__(512) void k_gemm2(
    const short* __restrict__ xbf, const float* __restrict__ xf,
    const short* __restrict__ WexpT, const float* __restrict__ expert_b,
    const int* __restrict__ cnt, const int* __restrict__ list,
    const int* __restrict__ desc, const int* __restrict__ ntl,
    float* __restrict__ out) {
  __shared__ __align__(16) char smem[65536];
  const int bx = (blockIdx.x % 8) * 17 + blockIdx.x / 8;  // T1 bijective, 136=8*17
  if (bx >= *ntl) return;
  int dsc = desc[bx];
  int e = dsc >> 16, mt = dsc & 0xffff;
  int ce = cnt[e];
  int mb = mt * 256;
  int rows = ce - mb; if (rows > 256) rows = 256;

  const int tid = threadIdx.x;
  const int lane = tid & 63, wave = tid >> 6;
  const int wr = wave >> 2, wcol = wave & 3;      // 2M x 4N wave grid
  const int fr = lane & 15, fg = lane >> 4;
  const int n0 = blockIdx.y * 256;
  const size_t ebase = (size_t)e << 20;
  const int lr = lane >> 2;
  const int gc8 = (((lane & 3) ^ ((lane >> 3) & 3)) << 3);

  const short* bP0 = WexpT + ebase + (size_t)(n0 + wave * 32 + lr) * HD + gc8;
  const short* bP1 = bP0 + (size_t)16 * HD;

  const short* aP0 = nullptr; const short* aP1 = nullptr;
  const float* aF = nullptr;
  int arow = 0, pc0 = 0, pc1 = 0;
  if constexpr (ABF) {
    int r0 = wave * 32 + lr, r1 = r0 + 16;
    int i0 = mb + r0; i0 = i0 < ce ? i0 : ce - 1;
    int i1 = mb + r1; i1 = i1 < ce ? i1 : ce - 1;
    aP0 = xbf + (size_t)list[(size_t)e * NTOK + i0] * HD + gc8;
    aP1 = xbf + (size_t)list[(size_t)e * NTOK + i1] * HD + gc8;
  } else {
    arow = tid >> 1;
    int idx = mb + arow; idx = idx < ce ? idx : ce - 1;
    aF = xf + (size_t)list[(size_t)e * NTOK + idx] * HD + (tid & 1) * 16;
    int c0 = (tid & 1) * 2, s = (arow >> 1) & 3;
    pc0 = (c0 ^ s) << 3; pc1 = ((c0 + 1) ^ s) << 3;
  }

  f32x4 acc[8][4];
#pragma unroll
  for (int i = 0; i < 8; ++i)
#pragma unroll
    for (int j = 0; j < 4; ++j) acc[i][j] = (f32x4){0.f, 0.f, 0.f, 0.f};

  auto STAGE = [&](int kt, int b) {
    const int k0 = kt * 32;
    gl16(smem + 32768 + b * 16384 + wave * 2048,        bP0 + k0);
    gl16(smem + 32768 + b * 16384 + wave * 2048 + 1024, bP1 + k0);
    if constexpr (ABF) {
      gl16(smem + b * 16384 + wave * 2048,        aP0 + k0);
      gl16(smem + b * 16384 + wave * 2048 + 1024, aP1 + k0);
    } else {
      f32x4 u0 = *(const f32x4*)(aF + k0);
      f32x4 u1 = *(const f32x4*)(aF + k0 + 4);
      f32x4 u2 = *(const f32x4*)(aF + k0 + 8);
      f32x4 u3 = *(const f32x4*)(aF + k0 + 12);
      short8 s0, s1;
#pragma unroll
      for (int q = 0; q < 4; ++q) {
        s0[q] = f2bh(u0[q]); s0[4 + q] = f2bh(u1[q]);
        s1[q] = f2bh(u2[q]); s1[4 + q] = f2bh(u3[q]);
      }
      short* As = (short*)(smem + b * 16384);
      *(short8*)(As + arow * 32 + pc0) = s0;
      *(short8*)(As + arow * 32 + pc1) = s1;
    }
  };
  const int csw = (fr >> 1) & 3;
  auto COMPUTE = [&](int b) {
    const short* As = (const short*)(smem + b * 16384);
    const short* Bs = (const short*)(smem + 32768 + b * 16384);
    short8 a[8], bb[4];
#pragma unroll
    for (int i = 0; i < 8; ++i)
      a[i] = *(const short8*)(As + (wr * 128 + i * 16 + fr) * 32 + ((fg ^ csw) << 3));
#pragma unroll
    for (int j = 0; j < 4; ++j)
      bb[j] = *(const short8*)(Bs + (wcol * 64 + j * 16 + fr) * 32 + ((fg ^ csw) << 3));
    __builtin_amdgcn_s_setprio(1);
#pragma unroll
    for (int i = 0; i < 8; ++i)
#pragma unroll
      for (int j = 0; j < 4; ++j)
        acc[i][j] = __builtin_amdgcn_mfma_f32_16x16x32_bf16(a[i], bb[j], acc[i][j], 0, 0, 0);
    __builtin_amdgcn_s_setprio(0);
  };

  STAGE(0, 0);
  __syncthreads();
#pragma unroll 1
  for (int kt = 0; kt < 32; kt += 2) {
    if (kt + 1 < 32) STAGE(kt + 1, 1);
    COMPUTE(0);
    __syncthreads();
    if (kt + 2 < 32) STAGE(kt + 2, 0);
    COMPUTE(1);
    __syncthreads();
  }

  // Coalesced epilogue: 16 passes, FULLY UNROLLED (static acc indices).
  float ebv[4];
#pragma unroll
  for (int j = 0; j < 4; ++j)
    ebv[j] = expert_b[e * HD + n0 + wcol * 64 + j * 16 + fr];
  float* buf = (float*)smem;  // [16][264] f32 = 16896 B
  const int row16 = tid >> 5, cc = tid & 31;
  const int listbase = (int)((size_t)e * NTOK) + mb;
#pragma unroll
  for (int p = 0; p < 16; ++p) {
    if (wr == (p >> 3)) {
#pragma unroll
      for (int j = 0; j < 4; ++j) {
        int col = wcol * 64 + j * 16 + fr;
#pragma unroll
        for (int q = 0; q < 4; ++q)
          buf[(fg * 4 + q) * 264 + col] = acc[p & 7][j][q] + ebv[j];
      }
    }
    __syncthreads();
    const int rr = p * 16 + row16;
    if (rr < rows) {
      int tok = list[listbase + rr];
      float* op = out + (size_t)tok * HD + n0 + cc * 8;
      *(f32x4*)op       = *(const f32x4*)(buf + row16 * 264 + cc * 8);
      *(f32x4*)(op + 4) = *(const f32x4*)(buf + row16 * 264 + cc * 8 + 4);
    }
    __syncthreads();
  }
}

// ---------------------------------------------------------------------------
extern "C" void kernel_launch(void* const* d_in, const int* in_sizes, int n_in,
                              void* d_out, int out_size, void* d_ws, size_t ws_size,
                              hipStream_t stream) {
  const float* x  = (const float*)d_in[0];
  const float* W1 = (const float*)d_in[1];
  const float* b1 = (const float*)d_in[2];
  const float* W2 = (const float*)d_in[3];
  const float* b2 = (const float*)d_in[4];
  const float* eW = (const float*)d_in[5];
  const float* eb = (const float*)d_in[6];
  float* out = (float*)d_out;
  char* ws = (char*)d_ws;

  const size_t XBF_BYTES = (size_t)NTOK * HD * 2;  // 67,108,864
  size_t need_rest = 16777216ull + 1048576 + 4194304 + 131072 * 3 + 1048576 + 4096;
  bool big = ws_size >= XBF_BYTES + need_rest;

  size_t off = 0;
  short* xbf = nullptr;
  if (big) { xbf = (short*)ws; off += XBF_BYTES; }
  short* WexpT  = (short*)(ws + off); off += 16777216;
  short* W1T    = (short*)(ws + off); off += 1048576;
  float* part   = (float*)(ws + off); off += 4194304;   // also partR (tier-A)
  int* sel      = (int*)(ws + off); off += 131072;
  int* flagged  = (int*)(ws + off); off += 131072;
  int* flagged2 = (int*)(ws + off); off += 131072;
  int* list     = (int*)(ws + off); off += 1048576;     // also W1lT before compact
  int* cnt      = (int*)(ws + off); off += 32;
  int* nflag    = (int*)(ws + off); off += 4;
  int* ntl      = (int*)(ws + off); off += 4;
  int* nflag2   = (int*)(ws + off); off += 24;
  int* desc     = (int*)(ws + off); off += 1088;
  if (ws_size < off) return;

  short* W1lT = (short*)list;  // 1 MB, live until k_compact

  hipMemsetAsync(cnt, 0, 44, stream);  // cnt[8], nflag, ntl, nflag2

  dim3 b256(256), b512(512);
  if (big) k_convert<<<dim3(16384), b256, 0, stream>>>(x, xbf);
  k_transpose_split<<<dim3(16, 32), b256, 0, stream>>>(W1, W1T, W1lT, 1024, 512);
  k_transpose<<<dim3(32, 32, 8), b256, 0, stream>>>(eW, WexpT, 1024, 1024);
  if (big)
    k_gemm1<true><<<dim3(256, 4), b256, 0, stream>>>(xbf, nullptr, W1T, b1, W2, part);
  else
    k_gemm1<false><<<dim3(256, 4), b256, 0, stream>>>(nullptr, x, W1T, b1, W2, part);
  k_combine<<<dim3(128), b256, 0, stream>>>(part, b2, sel, flagged, nflag);
  k_gemmR<<<dim3(256, 4), b256, 0, stream>>>(x, W1T, W1lT, b1, W2, flagged, nflag, part);
  k_combineR<<<dim3(128), b256, 0, stream>>>(part, b2, flagged, nflag, sel, flagged2, nflag2);
  k_recomputeB<<<dim3(128), b256, 0, stream>>>(x, W1, b1, W2, b2, flagged2, nflag2, sel);
  k_compact<<<dim3(128), b256, 0, stream>>>(sel, cnt, list);
  k_build_desc<<<dim3(1), dim3(64), 0, stream>>>(cnt, desc, ntl);
  if (big)
    k_gemm2<true><<<dim3(136, 4), b512, 0, stream>>>(xbf, nullptr, WexpT, eb, cnt, list, desc, ntl, out);
  else
    k_gemm2<false><<<dim3(136, 4), b512, 0, stream>>>(nullptr, x, WexpT, eb, cnt, list, desc, ntl, out);
}

// Round 14
// 356.363 us; speedup vs baseline: 3.3514x; 1.0170x over previous
//
#include <hip/hip_runtime.h>
#include <hip/hip_bf16.h>
#include <stdint.h>

#define NTOK 32768
#define HD 1024
#define FD 512
#define NEXP 8
#define TAU 0.05f
#define TAU2 4e-4f

typedef __attribute__((ext_vector_type(8))) short short8;
typedef __attribute__((ext_vector_type(4))) float f32x4;

__device__ __forceinline__ short f2bh(float f) {
  uint32_t u = __float_as_uint(f);
  return (short)((u + 0x7fffu + ((u >> 16) & 1u)) >> 16);
}
__device__ __forceinline__ float bh2f(short h) {
  return __uint_as_float(((uint32_t)(uint16_t)h) << 16);
}

__device__ __forceinline__ void gl16(void* lds, const void* g) {
  __builtin_amdgcn_global_load_lds(
      (const __attribute__((address_space(1))) void*)g,
      (__attribute__((address_space(3))) void*)lds, 16, 0, 0);
}

// ---------------------------------------------------------------------------
// Fused prep: [0,16384) x->xbf convert (skipped if xbf==null);
// [16384,24576) transpose eW->WexpT; [24576,25088) transpose+split W1.
// ---------------------------------------------------------------------------
__global__ __launch_bounds__(256) void k_prep(
    const float* __restrict__ x, short* __restrict__ xbf,
    const float* __restrict__ eW, short* __restrict__ WexpT,
    const float* __restrict__ W1, short* __restrict__ W1T,
    short* __restrict__ W1lT) {
  __shared__ float tile[32][33];
  const int g = blockIdx.x;
  if (g < 16384) {
    if (!xbf) return;
    size_t i = ((size_t)g * 256 + threadIdx.x) * 8;
    f32x4 v0 = *(const f32x4*)(x + i);
    f32x4 v1 = *(const f32x4*)(x + i + 4);
    short8 o;
#pragma unroll
    for (int q = 0; q < 4; ++q) { o[q] = f2bh(v0[q]); o[4 + q] = f2bh(v1[q]); }
    *(short8*)(xbf + i) = o;
    return;
  }
  int tx = threadIdx.x & 31, ty = threadIdx.x >> 5;
  if (g < 24576) {
    int idx = g - 16384;
    int ez = idx >> 10, rem = idx & 1023;
    int byy = rem >> 5, bxx = rem & 31;
    const float* src = eW + (size_t)ez * HD * HD;
    short* dst = WexpT + (size_t)ez * HD * HD;
    int c0 = bxx * 32, r0 = byy * 32;
#pragma unroll
    for (int i = 0; i < 32; i += 8)
      tile[ty + i][tx] = src[(size_t)(r0 + ty + i) * HD + c0 + tx];
    __syncthreads();
#pragma unroll
    for (int i = 0; i < 32; i += 8)
      dst[(size_t)(c0 + ty + i) * HD + r0 + tx] = f2bh(tile[tx][ty + i]);
    return;
  }
  {
    int idx = g - 24576;
    int byy = idx >> 4, bxx = idx & 15;
    int c0 = bxx * 32, r0 = byy * 32;
#pragma unroll
    for (int i = 0; i < 32; i += 8)
      tile[ty + i][tx] = W1[(size_t)(r0 + ty + i) * FD + c0 + tx];
    __syncthreads();
#pragma unroll
    for (int i = 0; i < 32; i += 8) {
      float v = tile[tx][ty + i];
      short h = f2bh(v);
      size_t di = (size_t)(c0 + ty + i) * 1024 + r0 + tx;
      W1T[di] = h;
      W1lT[di] = f2bh(v - bh2f(h));
    }
  }
}

// ---------------------------------------------------------------------------
// GEMM1: 128x128 tile, BK=32, 4 waves, single-buffer 2-barrier K-loop +
// T2 swizzle + T5 setprio. Fused MFMA logits epilogue. (R10-proven)
// ---------------------------------------------------------------------------
template <bool ABF>
__global__ __launch_bounds__(256) void k_gemm1(
    const short* __restrict__ xbf, const float* __restrict__ xf,
    const short* __restrict__ W1T, const float* __restrict__ b1,
    const float* __restrict__ W2, float* __restrict__ part) {
  __shared__ __align__(16) char smem[39168];

  const int tid = threadIdx.x;
  const int lane = tid & 63, wave = tid >> 6;
  const int wr = wave >> 1, wc = wave & 1;
  const int fr = lane & 15, fg = lane >> 4;
  const int bx = ((blockIdx.x & 7) << 5) | (blockIdx.x >> 3);
  const int m0 = bx * 128, n0 = blockIdx.y * 128;
  const int by = blockIdx.y;

  const int r0 = wave * 16 + (lane >> 2);
  const int lsw = (((lane & 3) ^ ((lane >> 3) & 3)) << 3);
  const short* b0p = W1T + (size_t)(n0 + r0) * HD + lsw;
  const short* b1p = W1T + (size_t)(n0 + r0 + 64) * HD + lsw;

  const short* a0p = nullptr; const short* a1p = nullptr;
  const float* aF = nullptr;
  int ar = 0, ah = 0, p0e = 0, p1e = 0;
  if constexpr (ABF) {
    a0p = xbf + (size_t)(m0 + r0) * HD + lsw;
    a1p = xbf + (size_t)(m0 + r0 + 64) * HD + lsw;
  } else {
    ar = tid >> 1; ah = tid & 1;
    aF = xf + (size_t)(m0 + ar) * HD + ah * 16;
    int s = (ar >> 1) & 3;
    p0e = ((2 * ah) ^ s) << 3;
    p1e = p0e ^ 8;
  }

  f32x4 acc[4][4];
#pragma unroll
  for (int i = 0; i < 4; ++i)
#pragma unroll
    for (int j = 0; j < 4; ++j) acc[i][j] = (f32x4){0.f, 0.f, 0.f, 0.f};

  const int csw = (fr >> 1) & 3;
  for (int k0 = 0; k0 < HD; k0 += 32) {
    gl16(smem + 8192 + wave * 1024, b0p + k0);
    gl16(smem + 12288 + wave * 1024, b1p + k0);
    if constexpr (ABF) {
      gl16(smem + wave * 1024, a0p + k0);
      gl16(smem + 4096 + wave * 1024, a1p + k0);
    } else {
      f32x4 u0 = *(const f32x4*)(aF + k0);
      f32x4 u1 = *(const f32x4*)(aF + k0 + 4);
      f32x4 u2 = *(const f32x4*)(aF + k0 + 8);
      f32x4 u3 = *(const f32x4*)(aF + k0 + 12);
      short8 s0, s1;
#pragma unroll
      for (int q = 0; q < 4; ++q) {
        s0[q] = f2bh(u0[q]); s0[4 + q] = f2bh(u1[q]);
        s1[q] = f2bh(u2[q]); s1[4 + q] = f2bh(u3[q]);
      }
      short* As = (short*)smem;
      *(short8*)(As + ar * 32 + p0e) = s0;
      *(short8*)(As + ar * 32 + p1e) = s1;
    }
    __syncthreads();
    {
      const short* As = (const short*)smem;
      const short* Bs = (const short*)(smem + 8192);
      short8 af[4], bf4[4];
#pragma unroll
      for (int i = 0; i < 4; ++i) {
        af[i]  = *(const short8*)(As + (wr * 64 + i * 16 + fr) * 32 + ((fg ^ csw) << 3));
        bf4[i] = *(const short8*)(Bs + (wc * 64 + i * 16 + fr) * 32 + ((fg ^ csw) << 3));
      }
      __builtin_amdgcn_s_setprio(1);
#pragma unroll
      for (int i = 0; i < 4; ++i)
#pragma unroll
        for (int j = 0; j < 4; ++j)
          acc[i][j] = __builtin_amdgcn_mfma_f32_16x16x32_bf16(af[i], bf4[j], acc[i][j], 0, 0, 0);
      __builtin_amdgcn_s_setprio(0);
    }
    __syncthreads();
  }

  short* hbf = (short*)smem;
  short* W2b = (short*)(smem + 34816);
  float b1j[4];
#pragma unroll
  for (int j = 0; j < 4; ++j) b1j[j] = b1[n0 + wc * 64 + j * 16 + fr];
  for (int q = tid; q < 2048; q += 256) {
    int col = q >> 7, k = q & 127;
    W2b[col * 136 + k] = (col < 8) ? f2bh(W2[(size_t)(n0 + k) * 8 + col]) : (short)0;
  }
#pragma unroll
  for (int i = 0; i < 4; ++i)
#pragma unroll
    for (int j = 0; j < 4; ++j) {
      int col = wc * 64 + j * 16 + fr;
#pragma unroll
      for (int q = 0; q < 4; ++q)
        hbf[(wr * 64 + i * 16 + fg * 4 + q) * 136 + col] =
            f2bh(fmaxf(acc[i][j][q] + b1j[j], 0.f));
    }
  __syncthreads();
#pragma unroll
  for (int rg = 0; rg < 2; ++rg) {
    int row16 = wave * 32 + rg * 16;
    f32x4 accl = (f32x4){0.f, 0.f, 0.f, 0.f};
#pragma unroll
    for (int kk = 0; kk < 4; ++kk) {
      short8 a = *(const short8*)(hbf + (row16 + fr) * 136 + kk * 32 + fg * 8);
      short8 b = *(const short8*)(W2b + fr * 136 + kk * 32 + fg * 8);
      accl = __builtin_amdgcn_mfma_f32_16x16x32_bf16(a, b, accl, 0, 0, 0);
    }
    if (fr < 8) {
      float* pp = part + (size_t)(m0 + row16 + fg * 4) * 32 + by * 8 + fr;
#pragma unroll
      for (int q = 0; q < 4; ++q) pp[(size_t)q * 32] = accl[q];
    }
  }
}

// ---------------------------------------------------------------------------
__global__ __launch_bounds__(256) void k_combine(
    const float* __restrict__ part, const float* __restrict__ b2,
    int* __restrict__ sel, int* __restrict__ flagged, int* __restrict__ nflag) {
  int t = blockIdx.x * 256 + threadIdx.x;
  const float* p = part + (size_t)t * 32;
  float lg[8];
#pragma unroll
  for (int e = 0; e < 8; ++e) lg[e] = p[e] + p[8 + e] + p[16 + e] + p[24 + e] + b2[e];
  int be = 0; float best = lg[0];
#pragma unroll
  for (int e = 1; e < 8; ++e) if (lg[e] > best) { best = lg[e]; be = e; }
  float second = -3.4e38f;
#pragma unroll
  for (int e = 0; e < 8; ++e) if (e != be && lg[e] > second) second = lg[e];
  sel[t] = be;
  if (best - second < TAU) {
    int ix = atomicAdd(nflag, 1);
    if (ix < NTOK) flagged[ix] = t;
  }
}

// ---------------------------------------------------------------------------
__global__ __launch_bounds__(256) void k_gemmR(
    const float* __restrict__ x, const short* __restrict__ W1hT,
    const short* __restrict__ W1lT, const float* __restrict__ b1,
    const float* __restrict__ W2, const int* __restrict__ flagged,
    const int* __restrict__ nflag, float* __restrict__ partR) {
  __shared__ __align__(16) char smem[37888];
  __shared__ int toks[128];
  short* Ah = (short*)smem;
  short* Al = (short*)(smem + 8192);

  int nf = *nflag; if (nf > NTOK) nf = NTOK;
  const int m0 = blockIdx.x * 128;
  if (m0 >= nf) return;
  const int tid = threadIdx.x;
  if (tid < 128) {
    int s = m0 + tid;
    toks[tid] = flagged[s < nf ? s : nf - 1];
  }
  __syncthreads();

  const int lane = tid & 63, wave = tid >> 6;
  const int wr = wave >> 1, wc = wave & 1;
  const int fr = lane & 15, fg = lane >> 4;
  const int n0 = blockIdx.y * 128;
  const int by = blockIdx.y;

  const int off0 = wave * 1024 + lane * 16;
  const int off1 = off0 + 4096;
  const int r0 = off0 >> 6, c0 = (off0 & 63) >> 1;
  const int r1 = off1 >> 6, c1 = (off1 & 63) >> 1;
  const short* bh0p = W1hT + (size_t)(n0 + r0) * HD + c0;
  const short* bh1p = W1hT + (size_t)(n0 + r1) * HD + c1;
  const short* bl0p = W1lT + (size_t)(n0 + r0) * HD + c0;
  const short* bl1p = W1lT + (size_t)(n0 + r1) * HD + c1;
  char* ldsBh0 = smem + 16384 + wave * 1024;
  char* ldsBh1 = smem + 16384 + wave * 1024 + 4096;
  char* ldsBl0 = smem + 24576 + wave * 1024;
  char* ldsBl1 = smem + 24576 + wave * 1024 + 4096;
  const int ar = tid >> 1, ah2 = tid & 1;
  const float* aF = x + (size_t)toks[ar] * HD + ah2 * 16;

  f32x4 acc[4][4];
#pragma unroll
  for (int i = 0; i < 4; ++i)
#pragma unroll
    for (int j = 0; j < 4; ++j) acc[i][j] = (f32x4){0.f, 0.f, 0.f, 0.f};

  for (int k0 = 0; k0 < HD; k0 += 32) {
    gl16(ldsBh0, bh0p + k0);
    gl16(ldsBh1, bh1p + k0);
    gl16(ldsBl0, bl0p + k0);
    gl16(ldsBl1, bl1p + k0);
    f32x4 u0 = *(const f32x4*)(aF + k0);
    f32x4 u1 = *(const f32x4*)(aF + k0 + 4);
    f32x4 u2 = *(const f32x4*)(aF + k0 + 8);
    f32x4 u3 = *(const f32x4*)(aF + k0 + 12);
    short8 sh0, sh1, sl0, sl1;
#pragma unroll
    for (int q = 0; q < 4; ++q) {
      { float f = u0[q]; short h = f2bh(f); sh0[q]     = h; sl0[q]     = f2bh(f - bh2f(h)); }
      { float f = u1[q]; short h = f2bh(f); sh0[4 + q] = h; sl0[4 + q] = f2bh(f - bh2f(h)); }
      { float f = u2[q]; short h = f2bh(f); sh1[q]     = h; sl1[q]     = f2bh(f - bh2f(h)); }
      { float f = u3[q]; short h = f2bh(f); sh1[4 + q] = h; sl1[4 + q] = f2bh(f - bh2f(h)); }
    }
    *(short8*)(Ah + ar * 32 + ah2 * 16)     = sh0;
    *(short8*)(Ah + ar * 32 + ah2 * 16 + 8) = sh1;
    *(short8*)(Al + ar * 32 + ah2 * 16)     = sl0;
    *(short8*)(Al + ar * 32 + ah2 * 16 + 8) = sl1;
    __syncthreads();
    short8 af[4], alf[4], bf[4], blf[4];
#pragma unroll
    for (int i = 0; i < 4; ++i) {
      int row = (wr * 64 + i * 16 + fr) * 32 + fg * 8;
      af[i]  = *(const short8*)(Ah + row);
      alf[i] = *(const short8*)(Al + row);
      int rowb = (wc * 64 + i * 16 + fr) * 32 + fg * 8;
      bf[i]  = *(const short8*)((short*)(smem + 16384) + rowb);
      blf[i] = *(const short8*)((short*)(smem + 24576) + rowb);
    }
#pragma unroll
    for (int i = 0; i < 4; ++i)
#pragma unroll
      for (int j = 0; j < 4; ++j) {
        acc[i][j] = __builtin_amdgcn_mfma_f32_16x16x32_bf16(af[i],  bf[j],  acc[i][j], 0, 0, 0);
        acc[i][j] = __builtin_amdgcn_mfma_f32_16x16x32_bf16(af[i],  blf[j], acc[i][j], 0, 0, 0);
        acc[i][j] = __builtin_amdgcn_mfma_f32_16x16x32_bf16(alf[i], bf[j],  acc[i][j], 0, 0, 0);
      }
    __syncthreads();
  }

  float* hl64 = (float*)smem;
  float* W2c  = (float*)(smem + 33024);
  *(f32x4*)(W2c + tid * 4) = *(const f32x4*)(W2 + (size_t)n0 * NEXP + tid * 4);
  float b1j[4];
#pragma unroll
  for (int j = 0; j < 4; ++j) b1j[j] = b1[n0 + wc * 64 + j * 16 + fr];

  for (int p = 0; p < 2; ++p) {
    if (wr == p) {
#pragma unroll
      for (int i = 0; i < 4; ++i)
#pragma unroll
        for (int j = 0; j < 4; ++j) {
          int col = wc * 64 + j * 16 + fr;
#pragma unroll
          for (int q = 0; q < 4; ++q)
            hl64[(i * 16 + fg * 4 + q) * 129 + col] = fmaxf(acc[i][j][q] + b1j[j], 0.f);
        }
    }
    __syncthreads();
    if (tid < 128) {
      int r2 = tid & 63, eh = tid >> 6;
      const float* hrow = hl64 + r2 * 129;
      const float* wcp = W2c + eh * 4;
      float s0 = 0.f, s1 = 0.f, s2 = 0.f, s3 = 0.f;
      for (int f = 0; f < 128; ++f) {
        float hv = hrow[f];
        s0 += hv * wcp[f * 8 + 0];
        s1 += hv * wcp[f * 8 + 1];
        s2 += hv * wcp[f * 8 + 2];
        s3 += hv * wcp[f * 8 + 3];
      }
      float* pp = partR + (size_t)(m0 + p * 64 + r2) * 32 + by * 8 + eh * 4;
      pp[0] = s0; pp[1] = s1; pp[2] = s2; pp[3] = s3;
    }
    __syncthreads();
  }
}

// ---------------------------------------------------------------------------
__global__ __launch_bounds__(256) void k_combineR(
    const float* __restrict__ partR, const float* __restrict__ b2,
    const int* __restrict__ flagged, const int* __restrict__ nflag,
    int* __restrict__ sel, int* __restrict__ flagged2, int* __restrict__ nflag2) {
  int nf = *nflag; if (nf > NTOK) nf = NTOK;
  int s = blockIdx.x * 256 + threadIdx.x;
  if (s >= nf) return;
  int t = flagged[s];
  const float* p = partR + (size_t)s * 32;
  float lg[8];
#pragma unroll
  for (int e = 0; e < 8; ++e) lg[e] = p[e] + p[8 + e] + p[16 + e] + p[24 + e] + b2[e];
  int be = 0; float best = lg[0];
#pragma unroll
  for (int e = 1; e < 8; ++e) if (lg[e] > best) { best = lg[e]; be = e; }
  float second = -3.4e38f;
#pragma unroll
  for (int e = 0; e < 8; ++e) if (e != be && lg[e] > second) second = lg[e];
  sel[t] = be;
  if (best - second < TAU2) {
    int ix = atomicAdd(nflag2, 1);
    if (ix < NTOK) flagged2[ix] = t;
  }
}

// ---------------------------------------------------------------------------
__global__ __launch_bounds__(256) void k_recomputeB(
    const float* __restrict__ x, const float* __restrict__ W1,
    const float* __restrict__ b1, const float* __restrict__ W2,
    const float* __restrict__ b2, const int* __restrict__ flagged2,
    const int* __restrict__ nflag2, int* __restrict__ sel) {
  __shared__ float xs[1024];
  __shared__ double hs[512];
  __shared__ double red[8][32];
  __shared__ double lgd[8];
  int nf = *nflag2; if (nf > NTOK) nf = NTOK;
  const int tid = threadIdx.x;
  for (int ti = blockIdx.x; ti < nf; ti += gridDim.x) {
    int t = flagged2[ti];
    __syncthreads();
    for (int q = tid; q < 1024; q += 256) xs[q] = x[(size_t)t * HD + q];
    __syncthreads();
    int f0 = tid * 2;
    double a0 = 0.0, a1 = 0.0;
    for (int h = 0; h < 1024; h += 4) {
      float2 w0 = *(const float2*)(W1 + (size_t)(h + 0) * FD + f0);
      float2 w1 = *(const float2*)(W1 + (size_t)(h + 1) * FD + f0);
      float2 w2 = *(const float2*)(W1 + (size_t)(h + 2) * FD + f0);
      float2 w3 = *(const float2*)(W1 + (size_t)(h + 3) * FD + f0);
      double x0 = (double)xs[h], x1 = (double)xs[h + 1];
      double x2 = (double)xs[h + 2], x3 = (double)xs[h + 3];
      a0 += x0 * (double)w0.x; a1 += x0 * (double)w0.y;
      a0 += x1 * (double)w1.x; a1 += x1 * (double)w1.y;
      a0 += x2 * (double)w2.x; a1 += x2 * (double)w2.y;
      a0 += x3 * (double)w3.x; a1 += x3 * (double)w3.y;
    }
    a0 += (double)b1[f0]; a1 += (double)b1[f0 + 1];
    hs[f0]     = a0 > 0.0 ? a0 : 0.0;
    hs[f0 + 1] = a1 > 0.0 ? a1 : 0.0;
    __syncthreads();
    {
      int e = tid >> 5, c = tid & 31;
      int fb = c * 16;
      double s = 0.0;
#pragma unroll
      for (int ff = 0; ff < 16; ++ff)
        s += hs[fb + ff] * (double)W2[(size_t)(fb + ff) * 8 + e];
      red[e][c] = s;
    }
    __syncthreads();
    if (tid < 8) {
      double s = 0.0;
#pragma unroll
      for (int c = 0; c < 32; ++c) s += red[tid][c];
      lgd[tid] = s + (double)b2[tid];
    }
    __syncthreads();
    if (tid == 0) {
      int be = 0; double best = lgd[0];
#pragma unroll
      for (int e = 1; e < 8; ++e) if (lgd[e] > best) { best = lgd[e]; be = e; }
      sel[t] = be;
    }
    __syncthreads();
  }
}

// ---------------------------------------------------------------------------
__global__ __launch_bounds__(256) void k_compact(
    const int* __restrict__ sel, int* __restrict__ cnt, int* __restrict__ list) {
  __shared__ int wcnt[4][8];
  __shared__ int woff[4][8];
  __shared__ int bbase[8];
  const int tid = threadIdx.x, lane = tid & 63, wave = tid >> 6;
  const int t = blockIdx.x * 256 + tid;
  const int e = sel[t];
  const unsigned long long ltmask = (1ull << lane) - 1ull;
  int rank = 0;
#pragma unroll
  for (int e2 = 0; e2 < 8; ++e2) {
    unsigned long long m = __ballot(e == e2);
    if (e2 == e) rank = __popcll(m & ltmask);
    if (lane == 0) wcnt[wave][e2] = __popcll(m);
  }
  __syncthreads();
  if (tid < 8) {
    int s0 = wcnt[0][tid], s1 = wcnt[1][tid], s2 = wcnt[2][tid], s3 = wcnt[3][tid];
    woff[0][tid] = 0; woff[1][tid] = s0; woff[2][tid] = s0 + s1; woff[3][tid] = s0 + s1 + s2;
    bbase[tid] = atomicAdd(&cnt[tid], s0 + s1 + s2 + s3);
  }
  __syncthreads();
  list[(size_t)e * NTOK + bbase[e] + woff[wave][e] + rank] = t;
}

__global__ void k_build_desc(const int* __restrict__ cnt, int* __restrict__ desc,
                             int* __restrict__ ntl) {
  if (threadIdx.x == 0 && blockIdx.x == 0) {
    int n = 0;
    for (int e = 0; e < 8; ++e) {
      int m = (cnt[e] + 127) >> 7;
      for (int i = 0; i < m; ++i) desc[n++] = (e << 16) | i;
    }
    *ntl = n;
  }
}

// ---------------------------------------------------------------------------
// GEMM2: R10-proven. 128x128 tile, BK=32, 4 waves, gathered A rows,
// single-buffer 2-barrier K-loop + T2 swizzle + T5 setprio, coalesced
// epilogue via [16][136] LDS.
// ---------------------------------------------------------------------------
template <bool ABF>
__global__ __launch_bounds__(256) void k_gemm2(
    const short* __restrict__ xbf, const float* __restrict__ xf,
    const short* __restrict__ WexpT, const float* __restrict__ expert_b,
    const int* __restrict__ cnt, const int* __restrict__ list,
    const int* __restrict__ desc, const int* __restrict__ ntl,
    float* __restrict__ out) {
  __shared__ __align__(16) char smem[16384];
  __shared__ int toks[128];
  const int bx = (blockIdx.x % 8) * 33 + blockIdx.x / 8;
  if (bx >= *ntl) return;
  int dsc = desc[bx];
  int e = dsc >> 16, mt = dsc & 0xffff;
  int ce = cnt[e];
  int mb = mt * 128;
  int rows = ce - mb; if (rows > 128) rows = 128;

  const int tid = threadIdx.x;
  if (tid < 128) {
    int idx = mb + tid;
    toks[tid] = list[(size_t)e * NTOK + (idx < ce ? idx : ce - 1)];
  }
  __syncthreads();

  const int lane = tid & 63, wave = tid >> 6;
  const int wr = wave >> 1, wc = wave & 1;
  const int fr = lane & 15, fg = lane >> 4;
  const int n0 = blockIdx.y * 128;

  const int r0 = wave * 16 + (lane >> 2);
  const int lsw = (((lane & 3) ^ ((lane >> 3) & 3)) << 3);
  const size_t ebase = (size_t)e << 20;
  const short* b0p = WexpT + ebase + (size_t)(n0 + r0) * HD + lsw;
  const short* b1p = WexpT + ebase + (size_t)(n0 + r0 + 64) * HD + lsw;

  const short* a0p = nullptr; const short* a1p = nullptr;
  const float* aF = nullptr;
  int ar = 0, ah = 0, p0e = 0, p1e = 0;
  if constexpr (ABF) {
    a0p = xbf + (size_t)toks[r0] * HD + lsw;
    a1p = xbf + (size_t)toks[r0 + 64] * HD + lsw;
  } else {
    ar = tid >> 1; ah = tid & 1;
    aF = xf + (size_t)toks[ar] * HD + ah * 16;
    int s = (ar >> 1) & 3;
    p0e = ((2 * ah) ^ s) << 3;
    p1e = p0e ^ 8;
  }

  f32x4 acc[4][4];
#pragma unroll
  for (int i = 0; i < 4; ++i)
#pragma unroll
    for (int j = 0; j < 4; ++j) acc[i][j] = (f32x4){0.f, 0.f, 0.f, 0.f};

  const int csw = (fr >> 1) & 3;
  for (int k0 = 0; k0 < HD; k0 += 32) {
    gl16(smem + 8192 + wave * 1024, b0p + k0);
    gl16(smem + 12288 + wave * 1024, b1p + k0);
    if constexpr (ABF) {
      gl16(smem + wave * 1024, a0p + k0);
      gl16(smem + 4096 + wave * 1024, a1p + k0);
    } else {
      f32x4 u0 = *(const f32x4*)(aF + k0);
      f32x4 u1 = *(const f32x4*)(aF + k0 + 4);
      f32x4 u2 = *(const f32x4*)(aF + k0 + 8);
      f32x4 u3 = *(const f32x4*)(aF + k0 + 12);
      short8 s0, s1;
#pragma unroll
      for (int q = 0; q < 4; ++q) {
        s0[q] = f2bh(u0[q]); s0[4 + q] = f2bh(u1[q]);
        s1[q] = f2bh(u2[q]); s1[4 + q] = f2bh(u3[q]);
      }
      short* As = (short*)smem;
      *(short8*)(As + ar * 32 + p0e) = s0;
      *(short8*)(As + ar * 32 + p1e) = s1;
    }
    __syncthreads();
    {
      const short* As = (const short*)smem;
      const short* Bs = (const short*)(smem + 8192);
      short8 af[4], bf4[4];
#pragma unroll
      for (int i = 0; i < 4; ++i) {
        af[i]  = *(const short8*)(As + (wr * 64 + i * 16 + fr) * 32 + ((fg ^ csw) << 3));
        bf4[i] = *(const short8*)(Bs + (wc * 64 + i * 16 + fr) * 32 + ((fg ^ csw) << 3));
      }
      __builtin_amdgcn_s_setprio(1);
#pragma unroll
      for (int i = 0; i < 4; ++i)
#pragma unroll
        for (int j = 0; j < 4; ++j)
          acc[i][j] = __builtin_amdgcn_mfma_f32_16x16x32_bf16(af[i], bf4[j], acc[i][j], 0, 0, 0);
      __builtin_amdgcn_s_setprio(0);
    }
    __syncthreads();
  }

  float ebv[4];
#pragma unroll
  for (int j = 0; j < 4; ++j) ebv[j] = expert_b[e * HD + n0 + wc * 64 + j * 16 + fr];
  float* buf = (float*)smem;
  const int row16 = tid >> 4, cc = tid & 15;
#pragma unroll
  for (int p = 0; p < 8; ++p) {
    if (wr == (p >> 2)) {
      const int i = p & 3;
#pragma unroll
      for (int j = 0; j < 4; ++j) {
        int col = wc * 64 + j * 16 + fr;
#pragma unroll
        for (int q = 0; q < 4; ++q)
          buf[(fg * 4 + q) * 136 + col] = acc[i][j][q] + ebv[j];
      }
    }
    __syncthreads();
    const int rr = p * 16 + row16;
    if (rr < rows) {
      float* op = out + (size_t)toks[rr] * HD + n0 + cc * 8;
      *(f32x4*)op       = *(const f32x4*)(buf + row16 * 136 + cc * 8);
      *(f32x4*)(op + 4) = *(const f32x4*)(buf + row16 * 136 + cc * 8 + 4);
    }
    __syncthreads();
  }
}

// ---------------------------------------------------------------------------
extern "C" void kernel_launch(void* const* d_in, const int* in_sizes, int n_in,
                              void* d_out, int out_size, void* d_ws, size_t ws_size,
                              hipStream_t stream) {
  const float* x  = (const float*)d_in[0];
  const float* W1 = (const float*)d_in[1];
  const float* b1 = (const float*)d_in[2];
  const float* W2 = (const float*)d_in[3];
  const float* b2 = (const float*)d_in[4];
  const float* eW = (const float*)d_in[5];
  const float* eb = (const float*)d_in[6];
  float* out = (float*)d_out;
  char* ws = (char*)d_ws;

  const size_t XBF_BYTES = (size_t)NTOK * HD * 2;
  size_t need_rest = 16777216ull + 1048576 + 4194304 + 131072 * 3 + 1048576 + 4096;
  bool big = ws_size >= XBF_BYTES + need_rest;

  size_t off = 0;
  short* xbf = nullptr;
  if (big) { xbf = (short*)ws; off += XBF_BYTES; }
  short* WexpT  = (short*)(ws + off); off += 16777216;
  short* W1T    = (short*)(ws + off); off += 1048576;
  float* part   = (float*)(ws + off); off += 4194304;
  int* sel      = (int*)(ws + off); off += 131072;
  int* flagged  = (int*)(ws + off); off += 131072;
  int* flagged2 = (int*)(ws + off); off += 131072;
  int* list     = (int*)(ws + off); off += 1048576;
  int* cnt      = (int*)(ws + off); off += 32;
  int* nflag    = (int*)(ws + off); off += 4;
  int* ntl      = (int*)(ws + off); off += 4;
  int* nflag2   = (int*)(ws + off); off += 24;
  int* desc     = (int*)(ws + off); off += 1088;
  if (ws_size < off) return;

  short* W1lT = (short*)list;

  hipMemsetAsync(cnt, 0, 44, stream);

  dim3 b256(256);
  k_prep<<<dim3(25088), b256, 0, stream>>>(x, big ? xbf : nullptr, eW, WexpT, W1, W1T, W1lT);
  if (big)
    k_gemm1<true><<<dim3(256, 4), b256, 0, stream>>>(xbf, nullptr, W1T, b1, W2, part);
  else
    k_gemm1<false><<<dim3(256, 4), b256, 0, stream>>>(nullptr, x, W1T, b1, W2, part);
  k_combine<<<dim3(128), b256, 0, stream>>>(part, b2, sel, flagged, nflag);
  k_gemmR<<<dim3(256, 4), b256, 0, stream>>>(x, W1T, W1lT, b1, W2, flagged, nflag, part);
  k_combineR<<<dim3(128), b256, 0, stream>>>(part, b2, flagged, nflag, sel, flagged2, nflag2);
  k_recomputeB<<<dim3(128), b256, 0, stream>>>(x, W1, b1, W2, b2, flagged2, nflag2, sel);
  k_compact<<<dim3(128), b256, 0, stream>>>(sel, cnt, list);
  k_build_desc<<<dim3(1), dim3(64), 0, stream>>>(cnt, desc, ntl);
  if (big)
    k_gemm2<true><<<dim3(264, 8), b256, 0, stream>>>(xbf, nullptr, WexpT, eb, cnt, list, desc, ntl, out);
  else
    k_gemm2<false><<<dim3(264, 8), b256, 0, stream>>>(nullptr, x, WexpT, eb, cnt, list, desc, ntl, out);
}

// Round 16
// 355.375 us; speedup vs baseline: 3.3607x; 1.0028x over previous
//
#include <hip/hip_runtime.h>
#include <hip/hip_bf16.h>
#include <stdint.h>

#define NTOK 32768
#define HD 1024
#define FD 512
#define NEXP 8
#define TAU 0.05f
#define TAU2 4e-4f

typedef __attribute__((ext_vector_type(8))) short short8;
typedef __attribute__((ext_vector_type(4))) float f32x4;

__device__ __forceinline__ short f2bh(float f) {
  uint32_t u = __float_as_uint(f);
  return (short)((u + 0x7fffu + ((u >> 16) & 1u)) >> 16);
}
__device__ __forceinline__ float bh2f(short h) {
  return __uint_as_float(((uint32_t)(uint16_t)h) << 16);
}

__device__ __forceinline__ void gl16(void* lds, const void* g) {
  __builtin_amdgcn_global_load_lds(
      (const __attribute__((address_space(1))) void*)g,
      (__attribute__((address_space(3))) void*)lds, 16, 0, 0);
}

// ---------------------------------------------------------------------------
// Fused prep: [0,16384) x->xbf convert (skipped if xbf==null);
// [16384,24576) transpose eW->WexpT; [24576,25088) transpose+split W1.
// ---------------------------------------------------------------------------
__global__ __launch_bounds__(256) void k_prep(
    const float* __restrict__ x, short* __restrict__ xbf,
    const float* __restrict__ eW, short* __restrict__ WexpT,
    const float* __restrict__ W1, short* __restrict__ W1T,
    short* __restrict__ W1lT) {
  __shared__ float tile[32][33];
  const int g = blockIdx.x;
  if (g < 16384) {
    if (!xbf) return;
    size_t i = ((size_t)g * 256 + threadIdx.x) * 8;
    f32x4 v0 = *(const f32x4*)(x + i);
    f32x4 v1 = *(const f32x4*)(x + i + 4);
    short8 o;
#pragma unroll
    for (int q = 0; q < 4; ++q) { o[q] = f2bh(v0[q]); o[4 + q] = f2bh(v1[q]); }
    *(short8*)(xbf + i) = o;
    return;
  }
  int tx = threadIdx.x & 31, ty = threadIdx.x >> 5;
  if (g < 24576) {
    int idx = g - 16384;
    int ez = idx >> 10, rem = idx & 1023;
    int byy = rem >> 5, bxx = rem & 31;
    const float* src = eW + (size_t)ez * HD * HD;
    short* dst = WexpT + (size_t)ez * HD * HD;
    int c0 = bxx * 32, r0 = byy * 32;
#pragma unroll
    for (int i = 0; i < 32; i += 8)
      tile[ty + i][tx] = src[(size_t)(r0 + ty + i) * HD + c0 + tx];
    __syncthreads();
#pragma unroll
    for (int i = 0; i < 32; i += 8)
      dst[(size_t)(c0 + ty + i) * HD + r0 + tx] = f2bh(tile[tx][ty + i]);
    return;
  }
  {
    int idx = g - 24576;
    int byy = idx >> 4, bxx = idx & 15;
    int c0 = bxx * 32, r0 = byy * 32;
#pragma unroll
    for (int i = 0; i < 32; i += 8)
      tile[ty + i][tx] = W1[(size_t)(r0 + ty + i) * FD + c0 + tx];
    __syncthreads();
#pragma unroll
    for (int i = 0; i < 32; i += 8) {
      float v = tile[tx][ty + i];
      short h = f2bh(v);
      size_t di = (size_t)(c0 + ty + i) * 1024 + r0 + tx;
      W1T[di] = h;
      W1lT[di] = f2bh(v - bh2f(h));
    }
  }
}

// ---------------------------------------------------------------------------
// GEMM1: 128x128 tile, BK=32, 4 waves, single-buffer 2-barrier K-loop +
// T2 swizzle + T5 setprio. Fused MFMA logits epilogue. (R10-proven)
// ---------------------------------------------------------------------------
template <bool ABF>
__global__ __launch_bounds__(256) void k_gemm1(
    const short* __restrict__ xbf, const float* __restrict__ xf,
    const short* __restrict__ W1T, const float* __restrict__ b1,
    const float* __restrict__ W2, float* __restrict__ part) {
  __shared__ __align__(16) char smem[39168];

  const int tid = threadIdx.x;
  const int lane = tid & 63, wave = tid >> 6;
  const int wr = wave >> 1, wc = wave & 1;
  const int fr = lane & 15, fg = lane >> 4;
  const int bx = ((blockIdx.x & 7) << 5) | (blockIdx.x >> 3);
  const int m0 = bx * 128, n0 = blockIdx.y * 128;
  const int by = blockIdx.y;

  const int r0 = wave * 16 + (lane >> 2);
  const int lsw = (((lane & 3) ^ ((lane >> 3) & 3)) << 3);
  const short* b0p = W1T + (size_t)(n0 + r0) * HD + lsw;
  const short* b1p = W1T + (size_t)(n0 + r0 + 64) * HD + lsw;

  const short* a0p = nullptr; const short* a1p = nullptr;
  const float* aF = nullptr;
  int ar = 0, ah = 0, p0e = 0, p1e = 0;
  if constexpr (ABF) {
    a0p = xbf + (size_t)(m0 + r0) * HD + lsw;
    a1p = xbf + (size_t)(m0 + r0 + 64) * HD + lsw;
  } else {
    ar = tid >> 1; ah = tid & 1;
    aF = xf + (size_t)(m0 + ar) * HD + ah * 16;
    int s = (ar >> 1) & 3;
    p0e = ((2 * ah) ^ s) << 3;
    p1e = p0e ^ 8;
  }

  f32x4 acc[4][4];
#pragma unroll
  for (int i = 0; i < 4; ++i)
#pragma unroll
    for (int j = 0; j < 4; ++j) acc[i][j] = (f32x4){0.f, 0.f, 0.f, 0.f};

  const int csw = (fr >> 1) & 3;
  for (int k0 = 0; k0 < HD; k0 += 32) {
    gl16(smem + 8192 + wave * 1024, b0p + k0);
    gl16(smem + 12288 + wave * 1024, b1p + k0);
    if constexpr (ABF) {
      gl16(smem + wave * 1024, a0p + k0);
      gl16(smem + 4096 + wave * 1024, a1p + k0);
    } else {
      f32x4 u0 = *(const f32x4*)(aF + k0);
      f32x4 u1 = *(const f32x4*)(aF + k0 + 4);
      f32x4 u2 = *(const f32x4*)(aF + k0 + 8);
      f32x4 u3 = *(const f32x4*)(aF + k0 + 12);
      short8 s0, s1;
#pragma unroll
      for (int q = 0; q < 4; ++q) {
        s0[q] = f2bh(u0[q]); s0[4 + q] = f2bh(u1[q]);
        s1[q] = f2bh(u2[q]); s1[4 + q] = f2bh(u3[q]);
      }
      short* As = (short*)smem;
      *(short8*)(As + ar * 32 + p0e) = s0;
      *(short8*)(As + ar * 32 + p1e) = s1;
    }
    __syncthreads();
    {
      const short* As = (const short*)smem;
      const short* Bs = (const short*)(smem + 8192);
      short8 af[4], bf4[4];
#pragma unroll
      for (int i = 0; i < 4; ++i) {
        af[i]  = *(const short8*)(As + (wr * 64 + i * 16 + fr) * 32 + ((fg ^ csw) << 3));
        bf4[i] = *(const short8*)(Bs + (wc * 64 + i * 16 + fr) * 32 + ((fg ^ csw) << 3));
      }
      __builtin_amdgcn_s_setprio(1);
#pragma unroll
      for (int i = 0; i < 4; ++i)
#pragma unroll
        for (int j = 0; j < 4; ++j)
          acc[i][j] = __builtin_amdgcn_mfma_f32_16x16x32_bf16(af[i], bf4[j], acc[i][j], 0, 0, 0);
      __builtin_amdgcn_s_setprio(0);
    }
    __syncthreads();
  }

  short* hbf = (short*)smem;
  short* W2b = (short*)(smem + 34816);
  float b1j[4];
#pragma unroll
  for (int j = 0; j < 4; ++j) b1j[j] = b1[n0 + wc * 64 + j * 16 + fr];
  for (int q = tid; q < 2048; q += 256) {
    int col = q >> 7, k = q & 127;
    W2b[col * 136 + k] = (col < 8) ? f2bh(W2[(size_t)(n0 + k) * 8 + col]) : (short)0;
  }
#pragma unroll
  for (int i = 0; i < 4; ++i)
#pragma unroll
    for (int j = 0; j < 4; ++j) {
      int col = wc * 64 + j * 16 + fr;
#pragma unroll
      for (int q = 0; q < 4; ++q)
        hbf[(wr * 64 + i * 16 + fg * 4 + q) * 136 + col] =
            f2bh(fmaxf(acc[i][j][q] + b1j[j], 0.f));
    }
  __syncthreads();
#pragma unroll
  for (int rg = 0; rg < 2; ++rg) {
    int row16 = wave * 32 + rg * 16;
    f32x4 accl = (f32x4){0.f, 0.f, 0.f, 0.f};
#pragma unroll
    for (int kk = 0; kk < 4; ++kk) {
      short8 a = *(const short8*)(hbf + (row16 + fr) * 136 + kk * 32 + fg * 8);
      short8 b = *(const short8*)(W2b + fr * 136 + kk * 32 + fg * 8);
      accl = __builtin_amdgcn_mfma_f32_16x16x32_bf16(a, b, accl, 0, 0, 0);
    }
    if (fr < 8) {
      float* pp = part + (size_t)(m0 + row16 + fg * 4) * 32 + by * 8 + fr;
#pragma unroll
      for (int q = 0; q < 4; ++q) pp[(size_t)q * 32] = accl[q];
    }
  }
}

// ---------------------------------------------------------------------------
__global__ __launch_bounds__(256) void k_combine(
    const float* __restrict__ part, const float* __restrict__ b2,
    int* __restrict__ sel, int* __restrict__ flagged, int* __restrict__ nflag) {
  int t = blockIdx.x * 256 + threadIdx.x;
  const float* p = part + (size_t)t * 32;
  float lg[8];
#pragma unroll
  for (int e = 0; e < 8; ++e) lg[e] = p[e] + p[8 + e] + p[16 + e] + p[24 + e] + b2[e];
  int be = 0; float best = lg[0];
#pragma unroll
  for (int e = 1; e < 8; ++e) if (lg[e] > best) { best = lg[e]; be = e; }
  float second = -3.4e38f;
#pragma unroll
  for (int e = 0; e < 8; ++e) if (e != be && lg[e] > second) second = lg[e];
  sel[t] = be;
  if (best - second < TAU) {
    int ix = atomicAdd(nflag, 1);
    if (ix < NTOK) flagged[ix] = t;
  }
}

// ---------------------------------------------------------------------------
__global__ __launch_bounds__(256) void k_gemmR(
    const float* __restrict__ x, const short* __restrict__ W1hT,
    const short* __restrict__ W1lT, const float* __restrict__ b1,
    const float* __restrict__ W2, const int* __restrict__ flagged,
    const int* __restrict__ nflag, float* __restrict__ partR) {
  __shared__ __align__(16) char smem[37888];
  __shared__ int toks[128];
  short* Ah = (short*)smem;
  short* Al = (short*)(smem + 8192);

  int nf = *nflag; if (nf > NTOK) nf = NTOK;
  const int m0 = blockIdx.x * 128;
  if (m0 >= nf) return;
  const int tid = threadIdx.x;
  if (tid < 128) {
    int s = m0 + tid;
    toks[tid] = flagged[s < nf ? s : nf - 1];
  }
  __syncthreads();

  const int lane = tid & 63, wave = tid >> 6;
  const int wr = wave >> 1, wc = wave & 1;
  const int fr = lane & 15, fg = lane >> 4;
  const int n0 = blockIdx.y * 128;
  const int by = blockIdx.y;

  const int off0 = wave * 1024 + lane * 16;
  const int off1 = off0 + 4096;
  const int r0 = off0 >> 6, c0 = (off0 & 63) >> 1;
  const int r1 = off1 >> 6, c1 = (off1 & 63) >> 1;
  const short* bh0p = W1hT + (size_t)(n0 + r0) * HD + c0;
  const short* bh1p = W1hT + (size_t)(n0 + r1) * HD + c1;
  const short* bl0p = W1lT + (size_t)(n0 + r0) * HD + c0;
  const short* bl1p = W1lT + (size_t)(n0 + r1) * HD + c1;
  char* ldsBh0 = smem + 16384 + wave * 1024;
  char* ldsBh1 = smem + 16384 + wave * 1024 + 4096;
  char* ldsBl0 = smem + 24576 + wave * 1024;
  char* ldsBl1 = smem + 24576 + wave * 1024 + 4096;
  const int ar = tid >> 1, ah2 = tid & 1;
  const float* aF = x + (size_t)toks[ar] * HD + ah2 * 16;

  f32x4 acc[4][4];
#pragma unroll
  for (int i = 0; i < 4; ++i)
#pragma unroll
    for (int j = 0; j < 4; ++j) acc[i][j] = (f32x4){0.f, 0.f, 0.f, 0.f};

  for (int k0 = 0; k0 < HD; k0 += 32) {
    gl16(ldsBh0, bh0p + k0);
    gl16(ldsBh1, bh1p + k0);
    gl16(ldsBl0, bl0p + k0);
    gl16(ldsBl1, bl1p + k0);
    f32x4 u0 = *(const f32x4*)(aF + k0);
    f32x4 u1 = *(const f32x4*)(aF + k0 + 4);
    f32x4 u2 = *(const f32x4*)(aF + k0 + 8);
    f32x4 u3 = *(const f32x4*)(aF + k0 + 12);
    short8 sh0, sh1, sl0, sl1;
#pragma unroll
    for (int q = 0; q < 4; ++q) {
      { float f = u0[q]; short h = f2bh(f); sh0[q]     = h; sl0[q]     = f2bh(f - bh2f(h)); }
      { float f = u1[q]; short h = f2bh(f); sh0[4 + q] = h; sl0[4 + q] = f2bh(f - bh2f(h)); }
      { float f = u2[q]; short h = f2bh(f); sh1[q]     = h; sl1[q]     = f2bh(f - bh2f(h)); }
      { float f = u3[q]; short h = f2bh(f); sh1[4 + q] = h; sl1[4 + q] = f2bh(f - bh2f(h)); }
    }
    *(short8*)(Ah + ar * 32 + ah2 * 16)     = sh0;
    *(short8*)(Ah + ar * 32 + ah2 * 16 + 8) = sh1;
    *(short8*)(Al + ar * 32 + ah2 * 16)     = sl0;
    *(short8*)(Al + ar * 32 + ah2 * 16 + 8) = sl1;
    __syncthreads();
    short8 af[4], alf[4], bf[4], blf[4];
#pragma unroll
    for (int i = 0; i < 4; ++i) {
      int row = (wr * 64 + i * 16 + fr) * 32 + fg * 8;
      af[i]  = *(const short8*)(Ah + row);
      alf[i] = *(const short8*)(Al + row);
      int rowb = (wc * 64 + i * 16 + fr) * 32 + fg * 8;
      bf[i]  = *(const short8*)((short*)(smem + 16384) + rowb);
      blf[i] = *(const short8*)((short*)(smem + 24576) + rowb);
    }
#pragma unroll
    for (int i = 0; i < 4; ++i)
#pragma unroll
      for (int j = 0; j < 4; ++j) {
        acc[i][j] = __builtin_amdgcn_mfma_f32_16x16x32_bf16(af[i],  bf[j],  acc[i][j], 0, 0, 0);
        acc[i][j] = __builtin_amdgcn_mfma_f32_16x16x32_bf16(af[i],  blf[j], acc[i][j], 0, 0, 0);
        acc[i][j] = __builtin_amdgcn_mfma_f32_16x16x32_bf16(alf[i], bf[j],  acc[i][j], 0, 0, 0);
      }
    __syncthreads();
  }

  float* hl64 = (float*)smem;
  float* W2c  = (float*)(smem + 33024);
  *(f32x4*)(W2c + tid * 4) = *(const f32x4*)(W2 + (size_t)n0 * NEXP + tid * 4);
  float b1j[4];
#pragma unroll
  for (int j = 0; j < 4; ++j) b1j[j] = b1[n0 + wc * 64 + j * 16 + fr];

  for (int p = 0; p < 2; ++p) {
    if (wr == p) {
#pragma unroll
      for (int i = 0; i < 4; ++i)
#pragma unroll
        for (int j = 0; j < 4; ++j) {
          int col = wc * 64 + j * 16 + fr;
#pragma unroll
          for (int q = 0; q < 4; ++q)
            hl64[(i * 16 + fg * 4 + q) * 129 + col] = fmaxf(acc[i][j][q] + b1j[j], 0.f);
        }
    }
    __syncthreads();
    if (tid < 128) {
      int r2 = tid & 63, eh = tid >> 6;
      const float* hrow = hl64 + r2 * 129;
      const float* wcp = W2c + eh * 4;
      float s0 = 0.f, s1 = 0.f, s2 = 0.f, s3 = 0.f;
      for (int f = 0; f < 128; ++f) {
        float hv = hrow[f];
        s0 += hv * wcp[f * 8 + 0];
        s1 += hv * wcp[f * 8 + 1];
        s2 += hv * wcp[f * 8 + 2];
        s3 += hv * wcp[f * 8 + 3];
      }
      float* pp = partR + (size_t)(m0 + p * 64 + r2) * 32 + by * 8 + eh * 4;
      pp[0] = s0; pp[1] = s1; pp[2] = s2; pp[3] = s3;
    }
    __syncthreads();
  }
}

// ---------------------------------------------------------------------------
__global__ __launch_bounds__(256) void k_combineR(
    const float* __restrict__ partR, const float* __restrict__ b2,
    const int* __restrict__ flagged, const int* __restrict__ nflag,
    int* __restrict__ sel, int* __restrict__ flagged2, int* __restrict__ nflag2) {
  int nf = *nflag; if (nf > NTOK) nf = NTOK;
  int s = blockIdx.x * 256 + threadIdx.x;
  if (s >= nf) return;
  int t = flagged[s];
  const float* p = partR + (size_t)s * 32;
  float lg[8];
#pragma unroll
  for (int e = 0; e < 8; ++e) lg[e] = p[e] + p[8 + e] + p[16 + e] + p[24 + e] + b2[e];
  int be = 0; float best = lg[0];
#pragma unroll
  for (int e = 1; e < 8; ++e) if (lg[e] > best) { best = lg[e]; be = e; }
  float second = -3.4e38f;
#pragma unroll
  for (int e = 0; e < 8; ++e) if (e != be && lg[e] > second) second = lg[e];
  sel[t] = be;
  if (best - second < TAU2) {
    int ix = atomicAdd(nflag2, 1);
    if (ix < NTOK) flagged2[ix] = t;
  }
}

// ---------------------------------------------------------------------------
__global__ __launch_bounds__(256) void k_recomputeB(
    const float* __restrict__ x, const float* __restrict__ W1,
    const float* __restrict__ b1, const float* __restrict__ W2,
    const float* __restrict__ b2, const int* __restrict__ flagged2,
    const int* __restrict__ nflag2, int* __restrict__ sel) {
  __shared__ float xs[1024];
  __shared__ double hs[512];
  __shared__ double red[8][32];
  __shared__ double lgd[8];
  int nf = *nflag2; if (nf > NTOK) nf = NTOK;
  const int tid = threadIdx.x;
  for (int ti = blockIdx.x; ti < nf; ti += gridDim.x) {
    int t = flagged2[ti];
    __syncthreads();
    for (int q = tid; q < 1024; q += 256) xs[q] = x[(size_t)t * HD + q];
    __syncthreads();
    int f0 = tid * 2;
    double a0 = 0.0, a1 = 0.0;
    for (int h = 0; h < 1024; h += 4) {
      float2 w0 = *(const float2*)(W1 + (size_t)(h + 0) * FD + f0);
      float2 w1 = *(const float2*)(W1 + (size_t)(h + 1) * FD + f0);
      float2 w2 = *(const float2*)(W1 + (size_t)(h + 2) * FD + f0);
      float2 w3 = *(const float2*)(W1 + (size_t)(h + 3) * FD + f0);
      double x0 = (double)xs[h], x1 = (double)xs[h + 1];
      double x2 = (double)xs[h + 2], x3 = (double)xs[h + 3];
      a0 += x0 * (double)w0.x; a1 += x0 * (double)w0.y;
      a0 += x1 * (double)w1.x; a1 += x1 * (double)w1.y;
      a0 += x2 * (double)w2.x; a1 += x2 * (double)w2.y;
      a0 += x3 * (double)w3.x; a1 += x3 * (double)w3.y;
    }
    a0 += (double)b1[f0]; a1 += (double)b1[f0 + 1];
    hs[f0]     = a0 > 0.0 ? a0 : 0.0;
    hs[f0 + 1] = a1 > 0.0 ? a1 : 0.0;
    __syncthreads();
    {
      int e = tid >> 5, c = tid & 31;
      int fb = c * 16;
      double s = 0.0;
#pragma unroll
      for (int ff = 0; ff < 16; ++ff)
        s += hs[fb + ff] * (double)W2[(size_t)(fb + ff) * 8 + e];
      red[e][c] = s;
    }
    __syncthreads();
    if (tid < 8) {
      double s = 0.0;
#pragma unroll
      for (int c = 0; c < 32; ++c) s += red[tid][c];
      lgd[tid] = s + (double)b2[tid];
    }
    __syncthreads();
    if (tid == 0) {
      int be = 0; double best = lgd[0];
#pragma unroll
      for (int e = 1; e < 8; ++e) if (lgd[e] > best) { best = lgd[e]; be = e; }
      sel[t] = be;
    }
    __syncthreads();
  }
}

// ---------------------------------------------------------------------------
__global__ __launch_bounds__(256) void k_compact(
    const int* __restrict__ sel, int* __restrict__ cnt, int* __restrict__ list) {
  __shared__ int wcnt[4][8];
  __shared__ int woff[4][8];
  __shared__ int bbase[8];
  const int tid = threadIdx.x, lane = tid & 63, wave = tid >> 6;
  const int t = blockIdx.x * 256 + tid;
  const int e = sel[t];
  const unsigned long long ltmask = (1ull << lane) - 1ull;
  int rank = 0;
#pragma unroll
  for (int e2 = 0; e2 < 8; ++e2) {
    unsigned long long m = __ballot(e == e2);
    if (e2 == e) rank = __popcll(m & ltmask);
    if (lane == 0) wcnt[wave][e2] = __popcll(m);
  }
  __syncthreads();
  if (tid < 8) {
    int s0 = wcnt[0][tid], s1 = wcnt[1][tid], s2 = wcnt[2][tid], s3 = wcnt[3][tid];
    woff[0][tid] = 0; woff[1][tid] = s0; woff[2][tid] = s0 + s1; woff[3][tid] = s0 + s1 + s2;
    bbase[tid] = atomicAdd(&cnt[tid], s0 + s1 + s2 + s3);
  }
  __syncthreads();
  list[(size_t)e * NTOK + bbase[e] + woff[wave][e] + rank] = t;
}

__global__ void k_build_desc(const int* __restrict__ cnt, int* __restrict__ desc,
                             int* __restrict__ ntl) {
  if (threadIdx.x == 0 && blockIdx.x == 0) {
    int n = 0;
    for (int e = 0; e < 8; ++e) {
      int m = (cnt[e] + 127) >> 7;
      for (int i = 0; i < m; ++i) desc[n++] = (e << 16) | i;
    }
    *ntl = n;
  }
}

// ---------------------------------------------------------------------------
// GEMM2: R10-proven. 128x128 tile, BK=32, 4 waves, gathered A rows,
// single-buffer 2-barrier K-loop + T2 swizzle + T5 setprio, coalesced
// epilogue via [16][136] LDS.
// ---------------------------------------------------------------------------
template <bool ABF>
__global__ __launch_bounds__(256) void k_gemm2(
    const short* __restrict__ xbf, const float* __restrict__ xf,
    const short* __restrict__ WexpT, const float* __restrict__ expert_b,
    const int* __restrict__ cnt, const int* __restrict__ list,
    const int* __restrict__ desc, const int* __restrict__ ntl,
    float* __restrict__ out) {
  __shared__ __align__(16) char smem[16384];
  __shared__ int toks[128];
  const int bx = (blockIdx.x % 8) * 33 + blockIdx.x / 8;
  if (bx >= *ntl) return;
  int dsc = desc[bx];
  int e = dsc >> 16, mt = dsc & 0xffff;
  int ce = cnt[e];
  int mb = mt * 128;
  int rows = ce - mb; if (rows > 128) rows = 128;

  const int tid = threadIdx.x;
  if (tid < 128) {
    int idx = mb + tid;
    toks[tid] = list[(size_t)e * NTOK + (idx < ce ? idx : ce - 1)];
  }
  __syncthreads();

  const int lane = tid & 63, wave = tid >> 6;
  const int wr = wave >> 1, wc = wave & 1;
  const int fr = lane & 15, fg = lane >> 4;
  const int n0 = blockIdx.y * 128;

  const int r0 = wave * 16 + (lane >> 2);
  const int lsw = (((lane & 3) ^ ((lane >> 3) & 3)) << 3);
  const size_t ebase = (size_t)e << 20;
  const short* b0p = WexpT + ebase + (size_t)(n0 + r0) * HD + lsw;
  const short* b1p = WexpT + ebase + (size_t)(n0 + r0 + 64) * HD + lsw;

  const short* a0p = nullptr; const short* a1p = nullptr;
  const float* aF = nullptr;
  int ar = 0, ah = 0, p0e = 0, p1e = 0;
  if constexpr (ABF) {
    a0p = xbf + (size_t)toks[r0] * HD + lsw;
    a1p = xbf + (size_t)toks[r0 + 64] * HD + lsw;
  } else {
    ar = tid >> 1; ah = tid & 1;
    aF = xf + (size_t)toks[ar] * HD + ah * 16;
    int s = (ar >> 1) & 3;
    p0e = ((2 * ah) ^ s) << 3;
    p1e = p0e ^ 8;
  }

  f32x4 acc[4][4];
#pragma unroll
  for (int i = 0; i < 4; ++i)
#pragma unroll
    for (int j = 0; j < 4; ++j) acc[i][j] = (f32x4){0.f, 0.f, 0.f, 0.f};

  const int csw = (fr >> 1) & 3;
  for (int k0 = 0; k0 < HD; k0 += 32) {
    gl16(smem + 8192 + wave * 1024, b0p + k0);
    gl16(smem + 12288 + wave * 1024, b1p + k0);
    if constexpr (ABF) {
      gl16(smem + wave * 1024, a0p + k0);
      gl16(smem + 4096 + wave * 1024, a1p + k0);
    } else {
      f32x4 u0 = *(const f32x4*)(aF + k0);
      f32x4 u1 = *(const f32x4*)(aF + k0 + 4);
      f32x4 u2 = *(const f32x4*)(aF + k0 + 8);
      f32x4 u3 = *(const f32x4*)(aF + k0 + 12);
      short8 s0, s1;
#pragma unroll
      for (int q = 0; q < 4; ++q) {
        s0[q] = f2bh(u0[q]); s0[4 + q] = f2bh(u1[q]);
        s1[q] = f2bh(u2[q]); s1[4 + q] = f2bh(u3[q]);
      }
      short* As = (short*)smem;
      *(short8*)(As + ar * 32 + p0e) = s0;
      *(short8*)(As + ar * 32 + p1e) = s1;
    }
    __syncthreads();
    {
      const short* As = (const short*)smem;
      const short* Bs = (const short*)(smem + 8192);
      short8 af[4], bf4[4];
#pragma unroll
      for (int i = 0; i < 4; ++i) {
        af[i]  = *(const short8*)(As + (wr * 64 + i * 16 + fr) * 32 + ((fg ^ csw) << 3));
        bf4[i] = *(const short8*)(Bs + (wc * 64 + i * 16 + fr) * 32 + ((fg ^ csw) << 3));
      }
      __builtin_amdgcn_s_setprio(1);
#pragma unroll
      for (int i = 0; i < 4; ++i)
#pragma unroll
        for (int j = 0; j < 4; ++j)
          acc[i][j] = __builtin_amdgcn_mfma_f32_16x16x32_bf16(af[i], bf4[j], acc[i][j], 0, 0, 0);
      __builtin_amdgcn_s_setprio(0);
    }
    __syncthreads();
  }

  float ebv[4];
#pragma unroll
  for (int j = 0; j < 4; ++j) ebv[j] = expert_b[e * HD + n0 + wc * 64 + j * 16 + fr];
  float* buf = (float*)smem;
  const int row16 = tid >> 4, cc = tid & 15;
#pragma unroll
  for (int p = 0; p < 8; ++p) {
    if (wr == (p >> 2)) {
      const int i = p & 3;
#pragma unroll
      for (int j = 0; j < 4; ++j) {
        int col = wc * 64 + j * 16 + fr;
#pragma unroll
        for (int q = 0; q < 4; ++q)
          buf[(fg * 4 + q) * 136 + col] = acc[i][j][q] + ebv[j];
      }
    }
    __syncthreads();
    const int rr = p * 16 + row16;
    if (rr < rows) {
      float* op = out + (size_t)toks[rr] * HD + n0 + cc * 8;
      *(f32x4*)op       = *(const f32x4*)(buf + row16 * 136 + cc * 8);
      *(f32x4*)(op + 4) = *(const f32x4*)(buf + row16 * 136 + cc * 8 + 4);
    }
    __syncthreads();
  }
}

// ---------------------------------------------------------------------------
extern "C" void kernel_launch(void* const* d_in, const int* in_sizes, int n_in,
                              void* d_out, int out_size, void* d_ws, size_t ws_size,
                              hipStream_t stream) {
  const float* x  = (const float*)d_in[0];
  const float* W1 = (const float*)d_in[1];
  const float* b1 = (const float*)d_in[2];
  const float* W2 = (const float*)d_in[3];
  const float* b2 = (const float*)d_in[4];
  const float* eW = (const float*)d_in[5];
  const float* eb = (const float*)d_in[6];
  float* out = (float*)d_out;
  char* ws = (char*)d_ws;

  const size_t XBF_BYTES = (size_t)NTOK * HD * 2;
  size_t need_rest = 16777216ull + 1048576 + 4194304 + 131072 * 3 + 1048576 + 4096;
  bool big = ws_size >= XBF_BYTES + need_rest;

  size_t off = 0;
  short* xbf = nullptr;
  if (big) { xbf = (short*)ws; off += XBF_BYTES; }
  short* WexpT  = (short*)(ws + off); off += 16777216;
  short* W1T    = (short*)(ws + off); off += 1048576;
  float* part   = (float*)(ws + off); off += 4194304;
  int* sel      = (int*)(ws + off); off += 131072;
  int* flagged  = (int*)(ws + off); off += 131072;
  int* flagged2 = (int*)(ws + off); off += 131072;
  int* list     = (int*)(ws + off); off += 1048576;
  int* cnt      = (int*)(ws + off); off += 32;
  int* nflag    = (int*)(ws + off); off += 4;
  int* ntl      = (int*)(ws + off); off += 4;
  int* nflag2   = (int*)(ws + off); off += 24;
  int* desc     = (int*)(ws + off); off += 1088;
  if (ws_size < off) return;

  short* W1lT = (short*)list;

  hipMemsetAsync(cnt, 0, 44, stream);

  dim3 b256(256);
  k_prep<<<dim3(25088), b256, 0, stream>>>(x, big ? xbf : nullptr, eW, WexpT, W1, W1T, W1lT);
  if (big)
    k_gemm1<true><<<dim3(256, 4), b256, 0, stream>>>(xbf, nullptr, W1T, b1, W2, part);
  else
    k_gemm1<false><<<dim3(256, 4), b256, 0, stream>>>(nullptr, x, W1T, b1, W2, part);
  k_combine<<<dim3(128), b256, 0, stream>>>(part, b2, sel, flagged, nflag);
  k_gemmR<<<dim3(256, 4), b256, 0, stream>>>(x, W1T, W1lT, b1, W2, flagged, nflag, part);
  k_combineR<<<dim3(128), b256, 0, stream>>>(part, b2, flagged, nflag, sel, flagged2, nflag2);
  k_recomputeB<<<dim3(128), b256, 0, stream>>>(x, W1, b1, W2, b2, flagged2, nflag2, sel);
  k_compact<<<dim3(128), b256, 0, stream>>>(sel, cnt, list);
  k_build_desc<<<dim3(1), dim3(64), 0, stream>>>(cnt, desc, ntl);
  if (big)
    k_gemm2<true><<<dim3(264, 8), b256, 0, stream>>>(xbf, nullptr, WexpT, eb, cnt, list, desc, ntl, out);
  else
    k_gemm2<false><<<dim3(264, 8), b256, 0, stream>>>(nullptr, x, WexpT, eb, cnt, list, desc, ntl, out);
}